// Round 4
// baseline (144.393 us; speedup 1.0000x reference)
//
#include <hip/hip_runtime.h>
#include <math.h>

#define B 2
#define V 6
#define C 256
#define Q 900
#define NH 8
#define HD 32
#define RADIUS 2.0f
#define QT 32
#define KT 64
#define NKT 15   // ceil(900/64)
#define M_ROWS (B * Q)   // 1800

// keypoints: [0,0,0],[R,0,0],[0,R,0],[-R,0,0]
__device__ __forceinline__ float kpx(int k) { return (k == 1) ? RADIUS : ((k == 3) ? -RADIUS : 0.f); }
__device__ __forceinline__ float kpy(int k) { return (k == 2) ? RADIUS : 0.f; }

__device__ __forceinline__ float tapv(const float* __restrict__ base, float xi, float yi, int W, int H) {
    if (xi < 0.f || xi > (float)(W - 1) || yi < 0.f || yi > (float)(H - 1)) return 0.f;
    int xc = (int)xi, yc = (int)yi;
    return base[yc * W + xc];
}

// One block per (b,q); thread t = channel c. Projection hoisted out of the
// level loop: ratio u/z and validity are level-independent; only the
// (exact, reference-order) grid arithmetic differs per level.
__global__ __launch_bounds__(256)
void sampler_kernel(const float* __restrict__ f0, const float* __restrict__ f1,
                    const float* __restrict__ refs, const float* __restrict__ intr,
                    const float* __restrict__ extr, float* __restrict__ sampled)
{
    int b = blockIdx.x / Q, q = blockIdx.x % Q;
    int t = threadIdx.x;
    __shared__ float sru[24], srv[24], sval[24];   // u/zs, v/zs, valid

    if (t < 24) {
        int v = t >> 2, kp = t & 3;
        const float* r = refs + (size_t)(b * Q + q) * 3;
        float px = r[0] + kpx(kp), py = r[1] + kpy(kp), pz = r[2];
        const float* E = extr + (size_t)(b * V + v) * 16;
        float cx = E[0] * px + E[1] * py + E[2]  * pz + E[3];
        float cy = E[4] * px + E[5] * py + E[6]  * pz + E[7];
        float cz = E[8] * px + E[9] * py + E[10] * pz + E[11];
        const float* Km = intr + (size_t)(b * V + v) * 9;
        float u = Km[0] * cx + Km[1] * cy + Km[2] * cz;
        float w = Km[3] * cx + Km[4] * cy + Km[5] * cz;
        float z = Km[6] * cx + Km[7] * cy + Km[8] * cz;
        float zs = (fabsf(z) > 1e-6f) ? z : 1e-6f;
        sru[t] = u / zs;
        srv[t] = w / zs;
        sval[t] = (z > 0.f) ? 1.f : 0.f;
    }
    __syncthreads();

    float cnt = 0.f;
    #pragma unroll
    for (int i = 0; i < 24; ++i) cnt += sval[i];
    cnt = fmaxf(cnt, 1.f);
    float icnt = 1.f / cnt;

    float acc_total = 0.f;
    #pragma unroll
    for (int lvl = 0; lvl < 2; ++lvl) {
        const int H = lvl ? 32 : 64;
        const int W = lvl ? 88 : 176;
        const int HW = H * W;
        const float* fm = lvl ? f1 : f0;

        float accl = 0.f;
        for (int i = 0; i < 24; ++i) {
            if (sval[i] == 0.f) continue;
            int v = i >> 2;
            // exact reference op order: ratio -> gx -> x
            float gx = 2.f * sru[i] / (float)(W - 1) - 1.f;
            float gy = 2.f * srv[i] / (float)(H - 1) - 1.f;
            float x = (gx + 1.f) * 0.5f * (float)(W - 1);
            float y = (gy + 1.f) * 0.5f * (float)(H - 1);
            float x0 = floorf(x), y0 = floorf(y);
            float wx1 = x - x0, wx0 = 1.f - wx1;
            float wy1 = y - y0, wy0 = 1.f - wy1;
            const float* base = fm + ((size_t)(b * V + v) * C + t) * (size_t)HW;
            accl += tapv(base, x0,       y0,       W, H) * (wx0 * wy0)
                  + tapv(base, x0 + 1.f, y0,       W, H) * (wx1 * wy0)
                  + tapv(base, x0,       y0 + 1.f, W, H) * (wx0 * wy1)
                  + tapv(base, x0 + 1.f, y0 + 1.f, W, H) * (wx1 * wy1);
        }
        acc_total += accl * icnt;
    }
    sampled[(size_t)(b * Q + q) * C + t] = acc_total * 0.5f;
}

// Fused transpose of 4 weight mats, LDS-tiled, coalesced both sides.
__global__ __launch_bounds__(256)
void wtrans4(const float* __restrict__ W0, const float* __restrict__ W1,
             const float* __restrict__ W2, const float* __restrict__ W3,
             float* __restrict__ T0, float* __restrict__ T1,
             float* __restrict__ T2, float* __restrict__ T3)
{
    __shared__ float tile[32][33];
    int mat = blockIdx.x >> 6, tpos = blockIdx.x & 63;
    const float* src = (mat == 0) ? W0 : (mat == 1) ? W1 : (mat == 2) ? W2 : W3;
    float* dst = (mat == 0) ? T0 : (mat == 1) ? T1 : (mat == 2) ? T2 : T3;
    int bx = (tpos & 7) * 32, by = (tpos >> 3) * 32;
    int r0 = threadIdx.x >> 5, cc = threadIdx.x & 31;
    #pragma unroll
    for (int i = 0; i < 4; ++i) {
        int r = r0 + 8 * i;
        tile[r][cc] = src[(size_t)(by + r) * C + bx + cc];
    }
    __syncthreads();
    #pragma unroll
    for (int i = 0; i < 4; ++i) {
        int r = r0 + 8 * i;
        dst[(size_t)(bx + r) * C + by + cc] = tile[cc][r];
    }
}

// Tiled fp32 GEMM: Y[m][n] = sum_k A[m][k] * Wt[k][n] + bias[n].
__device__ __forceinline__ void gemm_body(const float* __restrict__ A,
                                          const float* __restrict__ Wt,
                                          const float* __restrict__ bias,
                                          float* __restrict__ Y,
                                          int m0, int n0)
{
    __shared__ float As[32][64];   // k-major
    __shared__ float Bs[32][64];
    const int t = threadIdx.x;
    const int tx = t & 15, ty = t >> 4;
    const int mm = 4 * tx;
    const int nn = 4 * ty;

    float acc[4][4];
    {
        float4 bv4 = *(const float4*)(bias + n0 + nn);
        #pragma unroll
        for (int i = 0; i < 4; ++i) {
            acc[i][0] = bv4.x; acc[i][1] = bv4.y; acc[i][2] = bv4.z; acc[i][3] = bv4.w;
        }
    }

    const int am = t & 63;
    const int af = t >> 6;

    for (int ks = 0; ks < C; ks += 32) {
        __syncthreads();
        #pragma unroll
        for (int i = 0; i < 2; ++i) {
            int f = af + 4 * i;
            int gm = m0 + am;
            float4 v = make_float4(0.f, 0.f, 0.f, 0.f);
            if (gm < M_ROWS) v = *(const float4*)(A + (size_t)gm * C + ks + 4 * f);
            As[4 * f + 0][am] = v.x;
            As[4 * f + 1][am] = v.y;
            As[4 * f + 2][am] = v.z;
            As[4 * f + 3][am] = v.w;
        }
        #pragma unroll
        for (int i = 0; i < 2; ++i) {
            int idx = t + 256 * i;
            int kr = idx >> 4, nf = idx & 15;
            float4 v = *(const float4*)(Wt + (size_t)(ks + kr) * C + n0 + 4 * nf);
            *(float4*)(&Bs[kr][4 * nf]) = v;
        }
        __syncthreads();

        #pragma unroll
        for (int kk = 0; kk < 32; ++kk) {
            float4 a = *(const float4*)(&As[kk][mm]);
            float4 b = *(const float4*)(&Bs[kk][nn]);
            acc[0][0] += a.x * b.x; acc[0][1] += a.x * b.y; acc[0][2] += a.x * b.z; acc[0][3] += a.x * b.w;
            acc[1][0] += a.y * b.x; acc[1][1] += a.y * b.y; acc[1][2] += a.y * b.z; acc[1][3] += a.y * b.w;
            acc[2][0] += a.z * b.x; acc[2][1] += a.z * b.y; acc[2][2] += a.z * b.z; acc[2][3] += a.z * b.w;
            acc[3][0] += a.w * b.x; acc[3][1] += a.w * b.y; acc[3][2] += a.w * b.z; acc[3][3] += a.w * b.w;
        }
    }

    #pragma unroll
    for (int i = 0; i < 4; ++i) {
        int gm = m0 + mm + i;
        if (gm < M_ROWS) {
            *(float4*)(Y + (size_t)gm * C + n0 + nn) =
                make_float4(acc[i][0], acc[i][1], acc[i][2], acc[i][3]);
        }
    }
}

__global__ __launch_bounds__(256)
void gemm_qkv(const float* __restrict__ Xq, const float* __restrict__ Xs,
              const float* __restrict__ WqT, const float* __restrict__ WkT,
              const float* __restrict__ WvT,
              const float* __restrict__ bq, const float* __restrict__ bk,
              const float* __restrict__ bv,
              float* __restrict__ Yq, float* __restrict__ Yk, float* __restrict__ Yv)
{
    int z = blockIdx.z;
    const float* A    = (z == 0) ? Xq  : Xs;
    const float* Wt   = (z == 0) ? WqT : (z == 1) ? WkT : WvT;
    const float* bias = (z == 0) ? bq  : (z == 1) ? bk  : bv;
    float* Y          = (z == 0) ? Yq  : (z == 1) ? Yk  : Yv;
    gemm_body(A, Wt, bias, Y, blockIdx.x * 64, blockIdx.y * 64);
}

__global__ __launch_bounds__(256)
void gemm_one(const float* __restrict__ A, const float* __restrict__ Wt,
              const float* __restrict__ bias, float* __restrict__ Y)
{
    gemm_body(A, Wt, bias, Y, blockIdx.x * 64, blockIdx.y * 64);
}

// Flash attention v2: Q in registers, k-sliced PV accumulation in registers
// (no P->LDS roundtrip), final shfl-xor reduce across the 16 tx lanes.
// Thread (ty 0..15, tx 0..15): q rows {2ty,2ty+1}; keys {4tx..4tx+3};
// acc[2 rows][32 d] per thread (partial over its key slice).
__global__ __launch_bounds__(256, 2)
void attn_flash2(const float* __restrict__ qb, const float* __restrict__ kb,
                 const float* __restrict__ vb, float* __restrict__ ob)
{
    __shared__ float Qs[QT * 32];      // (r,d): r*32 + (d ^ ((r&7)<<2))
    __shared__ float Ks[KT * 32];      // (r,d): r*32 + (d ^ (((r>>2)&7)<<2))
    __shared__ float Vs[KT * 32];      // same swizzle as Ks (row-per-lane reads)

    const int tid = threadIdx.x;
    const int ty = tid >> 4;
    const int tx = tid & 15;
    const int b = blockIdx.z, h = blockIdx.y;
    const int q0 = blockIdx.x * QT;
    const int rA = 2 * ty, rB = rA + 1;

    // ---- stage Q once (coalesced, swizzled) ----
    {
        int r = tid >> 3, dc = (tid & 7) << 2;
        int qi = q0 + r;
        float4 qv = make_float4(0.f, 0.f, 0.f, 0.f);
        if (qi < Q) qv = *(const float4*)(qb + (size_t)(b * Q + qi) * C + h * HD + dc);
        *(float4*)(&Qs[r * 32 + (dc ^ ((r & 7) << 2))]) = qv;
    }
    __syncthreads();

    // ---- Q -> registers (pre-scaled) ----
    const float sc = 0.17677669529663687f; // 1/sqrt(32)
    float4 q0r[8], q1r[8];
    {
        const int swzA = (rA & 7) << 2, swzB = (rB & 7) << 2;
        #pragma unroll
        for (int dc8 = 0; dc8 < 8; ++dc8) {
            float4 a = *(const float4*)(&Qs[rA * 32 + ((4 * dc8) ^ swzA)]);
            float4 bqv = *(const float4*)(&Qs[rB * 32 + ((4 * dc8) ^ swzB)]);
            q0r[dc8] = make_float4(a.x * sc, a.y * sc, a.z * sc, a.w * sc);
            q1r[dc8] = make_float4(bqv.x * sc, bqv.y * sc, bqv.z * sc, bqv.w * sc);
        }
    }

    float m_[2] = { -1e30f, -1e30f };
    float l_[2] = { 0.f, 0.f };
    float4 acc0[8], acc1[8];
    #pragma unroll
    for (int i = 0; i < 8; ++i) {
        acc0[i] = make_float4(0.f, 0.f, 0.f, 0.f);
        acc1[i] = make_float4(0.f, 0.f, 0.f, 0.f);
    }

    const int kswz = (tx & 7) << 2;    // ((4tx+j)>>2)&7 == tx&7 for j<4

    for (int kt = 0; kt < NKT; ++kt) {
        const int k0 = kt * KT;
        __syncthreads();   // previous tile's readers done

        // ---- stage K, V (coalesced float4, swizzled) ----
        #pragma unroll
        for (int h2 = 0; h2 < 2; ++h2) {
            int r = (tid >> 3) + h2 * 32;
            int dc = (tid & 7) << 2;
            int ki = k0 + r;
            float4 kv = make_float4(0.f, 0.f, 0.f, 0.f);
            float4 vv = make_float4(0.f, 0.f, 0.f, 0.f);
            if (ki < Q) {
                kv = *(const float4*)(kb + (size_t)(b * Q + ki) * C + h * HD + dc);
                vv = *(const float4*)(vb + (size_t)(b * Q + ki) * C + h * HD + dc);
            }
            int sw = r * 32 + (dc ^ (((r >> 2) & 7) << 2));
            *(float4*)(&Ks[sw]) = kv;
            *(float4*)(&Vs[sw]) = vv;
        }
        __syncthreads();

        // ---- QK^T: s[2][4], Q from regs ----
        float s[2][4] = { {0.f,0.f,0.f,0.f}, {0.f,0.f,0.f,0.f} };
        #pragma unroll
        for (int j = 0; j < 4; ++j) {
            const int rk = (4 * tx + j) * 32;
            #pragma unroll
            for (int dc8 = 0; dc8 < 8; ++dc8) {
                float4 kv = *(const float4*)(&Ks[rk + ((4 * dc8) ^ kswz)]);
                s[0][j] += q0r[dc8].x * kv.x + q0r[dc8].y * kv.y + q0r[dc8].z * kv.z + q0r[dc8].w * kv.w;
                s[1][j] += q1r[dc8].x * kv.x + q1r[dc8].y * kv.y + q1r[dc8].z * kv.z + q1r[dc8].w * kv.w;
            }
        }
        #pragma unroll
        for (int j = 0; j < 4; ++j) {
            if (k0 + 4 * tx + j >= Q) { s[0][j] = -1e30f; s[1][j] = -1e30f; }
        }

        // ---- online softmax (row = 16 consecutive lanes) ----
        float al0, al1;
        {
            float tm = fmaxf(fmaxf(s[0][0], s[0][1]), fmaxf(s[0][2], s[0][3]));
            #pragma unroll
            for (int o = 1; o < 16; o <<= 1) tm = fmaxf(tm, __shfl_xor(tm, o));
            float mn = fmaxf(m_[0], tm);
            al0 = __expf(m_[0] - mn);
            float ps = 0.f;
            #pragma unroll
            for (int j = 0; j < 4; ++j) { float p = __expf(s[0][j] - mn); s[0][j] = p; ps += p; }
            #pragma unroll
            for (int o = 1; o < 16; o <<= 1) ps += __shfl_xor(ps, o);
            l_[0] = l_[0] * al0 + ps;
            m_[0] = mn;
        }
        {
            float tm = fmaxf(fmaxf(s[1][0], s[1][1]), fmaxf(s[1][2], s[1][3]));
            #pragma unroll
            for (int o = 1; o < 16; o <<= 1) tm = fmaxf(tm, __shfl_xor(tm, o));
            float mn = fmaxf(m_[1], tm);
            al1 = __expf(m_[1] - mn);
            float ps = 0.f;
            #pragma unroll
            for (int j = 0; j < 4; ++j) { float p = __expf(s[1][j] - mn); s[1][j] = p; ps += p; }
            #pragma unroll
            for (int o = 1; o < 16; o <<= 1) ps += __shfl_xor(ps, o);
            l_[1] = l_[1] * al1 + ps;
            m_[1] = mn;
        }

        // ---- rescale partial accumulators ----
        #pragma unroll
        for (int dc8 = 0; dc8 < 8; ++dc8) {
            acc0[dc8].x *= al0; acc0[dc8].y *= al0; acc0[dc8].z *= al0; acc0[dc8].w *= al0;
            acc1[dc8].x *= al1; acc1[dc8].y *= al1; acc1[dc8].z *= al1; acc1[dc8].w *= al1;
        }

        // ---- PV: each thread x its own 4 keys, all 32 d ----
        #pragma unroll
        for (int j = 0; j < 4; ++j) {
            const int rk = (4 * tx + j) * 32;
            const float pA = s[0][j], pB = s[1][j];
            #pragma unroll
            for (int dc8 = 0; dc8 < 8; ++dc8) {
                float4 vv = *(const float4*)(&Vs[rk + ((4 * dc8) ^ kswz)]);
                acc0[dc8].x += pA * vv.x; acc0[dc8].y += pA * vv.y;
                acc0[dc8].z += pA * vv.z; acc0[dc8].w += pA * vv.w;
                acc1[dc8].x += pB * vv.x; acc1[dc8].y += pB * vv.y;
                acc1[dc8].z += pB * vv.z; acc1[dc8].w += pB * vv.w;
            }
        }
    }

    // ---- reduce partial sums across the 16 tx lanes ----
    #pragma unroll
    for (int dc8 = 0; dc8 < 8; ++dc8) {
        #pragma unroll
        for (int o = 1; o < 16; o <<= 1) {
            acc0[dc8].x += __shfl_xor(acc0[dc8].x, o);
            acc0[dc8].y += __shfl_xor(acc0[dc8].y, o);
            acc0[dc8].z += __shfl_xor(acc0[dc8].z, o);
            acc0[dc8].w += __shfl_xor(acc0[dc8].w, o);
            acc1[dc8].x += __shfl_xor(acc1[dc8].x, o);
            acc1[dc8].y += __shfl_xor(acc1[dc8].y, o);
            acc1[dc8].z += __shfl_xor(acc1[dc8].z, o);
            acc1[dc8].w += __shfl_xor(acc1[dc8].w, o);
        }
    }

    // ---- write out: lanes tx 0..7 -> row A chunk tx, tx 8..15 -> row B ----
    const float invA = 1.f / l_[0];
    const float invB = 1.f / l_[1];
    const int qrowA = q0 + rA, qrowB = q0 + rB;
    #pragma unroll
    for (int dc8 = 0; dc8 < 8; ++dc8) {
        if (tx == dc8 && qrowA < Q) {
            *(float4*)(ob + (size_t)(b * Q + qrowA) * C + h * HD + 4 * dc8) =
                make_float4(acc0[dc8].x * invA, acc0[dc8].y * invA,
                            acc0[dc8].z * invA, acc0[dc8].w * invA);
        }
        if (tx == dc8 + 8 && qrowB < Q) {
            *(float4*)(ob + (size_t)(b * Q + qrowB) * C + h * HD + 4 * dc8) =
                make_float4(acc1[dc8].x * invB, acc1[dc8].y * invB,
                            acc1[dc8].z * invB, acc1[dc8].w * invB);
        }
    }
}

extern "C" void kernel_launch(void* const* d_in, const int* in_sizes, int n_in,
                              void* d_out, int out_size, void* d_ws, size_t ws_size,
                              hipStream_t stream) {
    const float* f0   = (const float*)d_in[0];
    const float* f1   = (const float*)d_in[1];
    const float* refs = (const float*)d_in[2];
    const float* intr = (const float*)d_in[3];
    const float* extr = (const float*)d_in[4];
    const float* qin  = (const float*)d_in[5];
    const float* Wq   = (const float*)d_in[6];
    const float* bq   = (const float*)d_in[7];
    const float* Wk   = (const float*)d_in[8];
    const float* bk   = (const float*)d_in[9];
    const float* Wv   = (const float*)d_in[10];
    const float* bv   = (const float*)d_in[11];
    const float* Wo   = (const float*)d_in[12];
    const float* bo   = (const float*)d_in[13];

    float* ws      = (float*)d_ws;
    float* sampled = ws;                  // 460800
    float* qbuf    = sampled + 460800;
    float* kbuf    = qbuf    + 460800;
    float* vbuf    = kbuf    + 460800;
    float* obuf    = vbuf    + 460800;
    float* WqT     = obuf    + 460800;    // 65536 each
    float* WkT     = WqT + 65536;
    float* WvT     = WkT + 65536;
    float* WoT     = WvT + 65536;
    float* out     = (float*)d_out;

    wtrans4<<<256, 256, 0, stream>>>(Wq, Wk, Wv, Wo, WqT, WkT, WvT, WoT);

    sampler_kernel<<<B * Q, 256, 0, stream>>>(f0, f1, refs, intr, extr, sampled);

    dim3 ggrid((M_ROWS + 63) / 64, C / 64, 3);
    gemm_qkv<<<ggrid, 256, 0, stream>>>(qin, sampled, WqT, WkT, WvT,
                                        bq, bk, bv, qbuf, kbuf, vbuf);

    dim3 agrid((Q + QT - 1) / QT, NH, B);
    attn_flash2<<<agrid, 256, 0, stream>>>(qbuf, kbuf, vbuf, obuf);

    dim3 ogrid((M_ROWS + 63) / 64, C / 64, 1);
    gemm_one<<<ogrid, 256, 0, stream>>>(obuf, WoT, bo, out);
}

// Round 5
// 94.903 us; speedup vs baseline: 1.5215x; 1.5215x over previous
//
#include <hip/hip_runtime.h>
#include <math.h>

#define B 2
#define V 6
#define C 256
#define Q 900
#define NH 8
#define HD 32
#define RADIUS 2.0f
#define M_ROWS (B * Q)   // 1800
#define NT 29            // ceil(900/32) key tiles

using short8 = __attribute__((ext_vector_type(8))) short;  // 8 bf16
using f32x4  = __attribute__((ext_vector_type(4))) float;

// f32 -> bf16 (RNE), bit pattern in a short
__device__ __forceinline__ short f2bf(float f) {
    union { float f; unsigned u; } x; x.f = f;
    unsigned r = x.u + 0x7fffu + ((x.u >> 16) & 1u);
    return (short)(r >> 16);
}

// keypoints: [0,0,0],[R,0,0],[0,R,0],[-R,0,0]
__device__ __forceinline__ float kpx(int k) { return (k == 1) ? RADIUS : ((k == 3) ? -RADIUS : 0.f); }
__device__ __forceinline__ float kpy(int k) { return (k == 2) ? RADIUS : 0.f; }

__device__ __forceinline__ float tapv(const float* __restrict__ base, float xi, float yi, int W, int H) {
    if (xi < 0.f || xi > (float)(W - 1) || yi < 0.f || yi > (float)(H - 1)) return 0.f;
    int xc = (int)xi, yc = (int)yi;
    return base[yc * W + xc];
}

// One block per (b,q); thread t = channel c.
__global__ __launch_bounds__(256)
void sampler_kernel(const float* __restrict__ f0, const float* __restrict__ f1,
                    const float* __restrict__ refs, const float* __restrict__ intr,
                    const float* __restrict__ extr, float* __restrict__ sampled)
{
    int b = blockIdx.x / Q, q = blockIdx.x % Q;
    int t = threadIdx.x;
    __shared__ float sru[24], srv[24], sval[24];   // u/zs, v/zs, valid

    if (t < 24) {
        int v = t >> 2, kp = t & 3;
        const float* r = refs + (size_t)(b * Q + q) * 3;
        float px = r[0] + kpx(kp), py = r[1] + kpy(kp), pz = r[2];
        const float* E = extr + (size_t)(b * V + v) * 16;
        float cx = E[0] * px + E[1] * py + E[2]  * pz + E[3];
        float cy = E[4] * px + E[5] * py + E[6]  * pz + E[7];
        float cz = E[8] * px + E[9] * py + E[10] * pz + E[11];
        const float* Km = intr + (size_t)(b * V + v) * 9;
        float u = Km[0] * cx + Km[1] * cy + Km[2] * cz;
        float w = Km[3] * cx + Km[4] * cy + Km[5] * cz;
        float z = Km[6] * cx + Km[7] * cy + Km[8] * cz;
        float zs = (fabsf(z) > 1e-6f) ? z : 1e-6f;
        sru[t] = u / zs;
        srv[t] = w / zs;
        sval[t] = (z > 0.f) ? 1.f : 0.f;
    }
    __syncthreads();

    float cnt = 0.f;
    #pragma unroll
    for (int i = 0; i < 24; ++i) cnt += sval[i];
    cnt = fmaxf(cnt, 1.f);
    float icnt = 1.f / cnt;

    float acc_total = 0.f;
    #pragma unroll
    for (int lvl = 0; lvl < 2; ++lvl) {
        const int H = lvl ? 32 : 64;
        const int W = lvl ? 88 : 176;
        const int HW = H * W;
        const float* fm = lvl ? f1 : f0;

        float accl = 0.f;
        for (int i = 0; i < 24; ++i) {
            if (sval[i] == 0.f) continue;
            int v = i >> 2;
            float gx = 2.f * sru[i] / (float)(W - 1) - 1.f;
            float gy = 2.f * srv[i] / (float)(H - 1) - 1.f;
            float x = (gx + 1.f) * 0.5f * (float)(W - 1);
            float y = (gy + 1.f) * 0.5f * (float)(H - 1);
            float x0 = floorf(x), y0 = floorf(y);
            float wx1 = x - x0, wx0 = 1.f - wx1;
            float wy1 = y - y0, wy0 = 1.f - wy1;
            const float* base = fm + ((size_t)(b * V + v) * C + t) * (size_t)HW;
            accl += tapv(base, x0,       y0,       W, H) * (wx0 * wy0)
                  + tapv(base, x0 + 1.f, y0,       W, H) * (wx1 * wy0)
                  + tapv(base, x0,       y0 + 1.f, W, H) * (wx0 * wy1)
                  + tapv(base, x0 + 1.f, y0 + 1.f, W, H) * (wx1 * wy1);
        }
        acc_total += accl * icnt;
    }
    sampled[(size_t)(b * Q + q) * C + t] = acc_total * 0.5f;
}

// Fused transpose of 4 weight mats (for the fp32 GEMMs).
__global__ __launch_bounds__(256)
void wtrans4(const float* __restrict__ W0, const float* __restrict__ W1,
             const float* __restrict__ W2, const float* __restrict__ W3,
             float* __restrict__ T0, float* __restrict__ T1,
             float* __restrict__ T2, float* __restrict__ T3)
{
    __shared__ float tile[32][33];
    int mat = blockIdx.x >> 6, tpos = blockIdx.x & 63;
    const float* src = (mat == 0) ? W0 : (mat == 1) ? W1 : (mat == 2) ? W2 : W3;
    float* dst = (mat == 0) ? T0 : (mat == 1) ? T1 : (mat == 2) ? T2 : T3;
    int bx = (tpos & 7) * 32, by = (tpos >> 3) * 32;
    int r0 = threadIdx.x >> 5, cc = threadIdx.x & 31;
    #pragma unroll
    for (int i = 0; i < 4; ++i) {
        int r = r0 + 8 * i;
        tile[r][cc] = src[(size_t)(by + r) * C + bx + cc];
    }
    __syncthreads();
    #pragma unroll
    for (int i = 0; i < 4; ++i) {
        int r = r0 + 8 * i;
        dst[(size_t)(bx + r) * C + by + cc] = tile[cc][r];
    }
}

// Tiled fp32 GEMM: Y[m][n] = sum_k A[m][k] * Wt[k][n] + bias[n].
__device__ __forceinline__ void gemm_body(const float* __restrict__ A,
                                          const float* __restrict__ Wt,
                                          const float* __restrict__ bias,
                                          float* __restrict__ Y,
                                          int m0, int n0)
{
    __shared__ float As[32][64];   // k-major
    __shared__ float Bs[32][64];
    const int t = threadIdx.x;
    const int tx = t & 15, ty = t >> 4;
    const int mm = 4 * tx;
    const int nn = 4 * ty;

    float acc[4][4];
    {
        float4 bv4 = *(const float4*)(bias + n0 + nn);
        #pragma unroll
        for (int i = 0; i < 4; ++i) {
            acc[i][0] = bv4.x; acc[i][1] = bv4.y; acc[i][2] = bv4.z; acc[i][3] = bv4.w;
        }
    }

    const int am = t & 63;
    const int af = t >> 6;

    for (int ks = 0; ks < C; ks += 32) {
        __syncthreads();
        #pragma unroll
        for (int i = 0; i < 2; ++i) {
            int f = af + 4 * i;
            int gm = m0 + am;
            float4 v = make_float4(0.f, 0.f, 0.f, 0.f);
            if (gm < M_ROWS) v = *(const float4*)(A + (size_t)gm * C + ks + 4 * f);
            As[4 * f + 0][am] = v.x;
            As[4 * f + 1][am] = v.y;
            As[4 * f + 2][am] = v.z;
            As[4 * f + 3][am] = v.w;
        }
        #pragma unroll
        for (int i = 0; i < 2; ++i) {
            int idx = t + 256 * i;
            int kr = idx >> 4, nf = idx & 15;
            float4 v = *(const float4*)(Wt + (size_t)(ks + kr) * C + n0 + 4 * nf);
            *(float4*)(&Bs[kr][4 * nf]) = v;
        }
        __syncthreads();

        #pragma unroll
        for (int kk = 0; kk < 32; ++kk) {
            float4 a = *(const float4*)(&As[kk][mm]);
            float4 b = *(const float4*)(&Bs[kk][nn]);
            acc[0][0] += a.x * b.x; acc[0][1] += a.x * b.y; acc[0][2] += a.x * b.z; acc[0][3] += a.x * b.w;
            acc[1][0] += a.y * b.x; acc[1][1] += a.y * b.y; acc[1][2] += a.y * b.z; acc[1][3] += a.y * b.w;
            acc[2][0] += a.z * b.x; acc[2][1] += a.z * b.y; acc[2][2] += a.z * b.z; acc[2][3] += a.z * b.w;
            acc[3][0] += a.w * b.x; acc[3][1] += a.w * b.y; acc[3][2] += a.w * b.z; acc[3][3] += a.w * b.w;
        }
    }

    #pragma unroll
    for (int i = 0; i < 4; ++i) {
        int gm = m0 + mm + i;
        if (gm < M_ROWS) {
            *(float4*)(Y + (size_t)gm * C + n0 + nn) =
                make_float4(acc[i][0], acc[i][1], acc[i][2], acc[i][3]);
        }
    }
}

__global__ __launch_bounds__(256)
void gemm_qkv(const float* __restrict__ Xq, const float* __restrict__ Xs,
              const float* __restrict__ WqT, const float* __restrict__ WkT,
              const float* __restrict__ WvT,
              const float* __restrict__ bq, const float* __restrict__ bk,
              const float* __restrict__ bv,
              float* __restrict__ Yq, float* __restrict__ Yk, float* __restrict__ Yv)
{
    int z = blockIdx.z;
    const float* A    = (z == 0) ? Xq  : Xs;
    const float* Wt   = (z == 0) ? WqT : (z == 1) ? WkT : WvT;
    const float* bias = (z == 0) ? bq  : (z == 1) ? bk  : bv;
    float* Y          = (z == 0) ? Yq  : (z == 1) ? Yk  : Yv;
    gemm_body(A, Wt, bias, Y, blockIdx.x * 64, blockIdx.y * 64);
}

__global__ __launch_bounds__(256)
void gemm_one(const float* __restrict__ A, const float* __restrict__ Wt,
              const float* __restrict__ bias, float* __restrict__ Y)
{
    gemm_body(A, Wt, bias, Y, blockIdx.x * 64, blockIdx.y * 64);
}

// MFMA flash attention.
// Block = 128 threads = 2 waves; wave w owns q-rows [q0+16w, q0+16w+16).
// Per 32-key tile:
//   S^T = mfma_16x16x32_bf16(A=K-tile, B=Q-frag)  (two 16-key halves)
//     -> lane holds S^T[key=4g+reg][q=lane&15]; softmax per q-col via shfl_xor(16,32)
//   P packed to bf16 in-lane == x32 A-fragment (consistent key permutation)
//   O += mfma_16x16x32_bf16(A=P, B=V^T-slots)   (two 16-d halves)
// K/V staged f32->bf16 into LDS; next tile prefetched into regs during compute.
__global__ __launch_bounds__(128)
void attn_mfma(const float* __restrict__ qb, const float* __restrict__ kb,
               const float* __restrict__ vb, float* __restrict__ ob)
{
    __shared__ __align__(16) short Ks[32][40];   // [key][dim], padded
    __shared__ __align__(16) short VT[32][36];   // [dim][key], padded

    const int tid = threadIdx.x;
    const int lane = tid & 63;
    const int w = tid >> 6;
    const int l15 = lane & 15, g = lane >> 4;
    const int b = blockIdx.z, h = blockIdx.y;
    const int q0 = blockIdx.x * 32 + w * 16;

    // ---- Q fragment (scaled, bf16) ----
    short8 qf;
    {
        const float sc = 0.17677669529663687f; // 1/sqrt(32)
        int qrow = q0 + l15;
        float4 a = make_float4(0.f,0.f,0.f,0.f), c2 = make_float4(0.f,0.f,0.f,0.f);
        if (qrow < Q) {
            const float* p = qb + (size_t)(b * Q + qrow) * C + h * HD + 8 * g;
            a  = *(const float4*)p;
            c2 = *(const float4*)(p + 4);
        }
        qf[0]=f2bf(a.x*sc);  qf[1]=f2bf(a.y*sc);  qf[2]=f2bf(a.z*sc);  qf[3]=f2bf(a.w*sc);
        qf[4]=f2bf(c2.x*sc); qf[5]=f2bf(c2.y*sc); qf[6]=f2bf(c2.z*sc); qf[7]=f2bf(c2.w*sc);
    }

    float m_ = -1e30f, l_ = 0.f;
    f32x4 acc0 = {0.f,0.f,0.f,0.f}, acc1 = {0.f,0.f,0.f,0.f};
    const f32x4 z4 = {0.f,0.f,0.f,0.f};

    // staging assignment: 2 tasks/thread, task id -> (key, 4-dim chunk)
    const int keyA = tid >> 3,        ccA = tid & 7;          // ids 0..127
    const int keyB = (128 + tid) >> 3, ccB = tid & 7;         // ids 128..255
    float4 kregA, vregA, kregB, vregB;

    #define LOAD_TILE(t)                                                        \
    {                                                                           \
        int gkA = (t) * 32 + keyA, gkB = (t) * 32 + keyB;                       \
        if (gkA < Q) {                                                          \
            const float* kp = kb + (size_t)(b*Q+gkA)*C + h*HD + 4*ccA;          \
            const float* vp = vb + (size_t)(b*Q+gkA)*C + h*HD + 4*ccA;          \
            kregA = *(const float4*)kp; vregA = *(const float4*)vp;             \
        } else { kregA = make_float4(0.f,0.f,0.f,0.f); vregA = kregA; }         \
        if (gkB < Q) {                                                          \
            const float* kp = kb + (size_t)(b*Q+gkB)*C + h*HD + 4*ccB;          \
            const float* vp = vb + (size_t)(b*Q+gkB)*C + h*HD + 4*ccB;          \
            kregB = *(const float4*)kp; vregB = *(const float4*)vp;             \
        } else { kregB = make_float4(0.f,0.f,0.f,0.f); vregB = kregB; }         \
    }

    LOAD_TILE(0);

    for (int t = 0; t < NT; ++t) {
        __syncthreads();   // previous tile's readers done
        // ---- write staged regs to LDS (bf16) ----
        {
            short4 ks;
            ks.x = f2bf(kregA.x); ks.y = f2bf(kregA.y); ks.z = f2bf(kregA.z); ks.w = f2bf(kregA.w);
            *(short4*)&Ks[keyA][4 * ccA] = ks;
            VT[4*ccA+0][keyA] = f2bf(vregA.x);
            VT[4*ccA+1][keyA] = f2bf(vregA.y);
            VT[4*ccA+2][keyA] = f2bf(vregA.z);
            VT[4*ccA+3][keyA] = f2bf(vregA.w);
            ks.x = f2bf(kregB.x); ks.y = f2bf(kregB.y); ks.z = f2bf(kregB.z); ks.w = f2bf(kregB.w);
            *(short4*)&Ks[keyB][4 * ccB] = ks;
            VT[4*ccB+0][keyB] = f2bf(vregB.x);
            VT[4*ccB+1][keyB] = f2bf(vregB.y);
            VT[4*ccB+2][keyB] = f2bf(vregB.z);
            VT[4*ccB+3][keyB] = f2bf(vregB.w);
        }
        __syncthreads();   // LDS ready

        if (t + 1 < NT) LOAD_TILE(t + 1);   // prefetch overlaps compute

        // ---- QK^T (swapped): S^T[key][q] ----
        short8 kf0 = *(const short8*)&Ks[l15][8 * g];
        short8 kf1 = *(const short8*)&Ks[16 + l15][8 * g];
        f32x4 s0 = __builtin_amdgcn_mfma_f32_16x16x32_bf16(kf0, qf, z4, 0, 0, 0);
        f32x4 s1 = __builtin_amdgcn_mfma_f32_16x16x32_bf16(kf1, qf, z4, 0, 0, 0);

        const int kbase = t * 32;
        if (kbase + 32 > Q) {   // only last tile
            #pragma unroll
            for (int j = 0; j < 4; ++j) {
                if (kbase + 4 * g + j      >= Q) s0[j] = -1e30f;
                if (kbase + 16 + 4 * g + j >= Q) s1[j] = -1e30f;
            }
        }

        // ---- online softmax per q-col (lane&15) ----
        float tm = fmaxf(fmaxf(fmaxf(s0[0], s0[1]), fmaxf(s0[2], s0[3])),
                         fmaxf(fmaxf(s1[0], s1[1]), fmaxf(s1[2], s1[3])));
        tm = fmaxf(tm, __shfl_xor(tm, 16));
        tm = fmaxf(tm, __shfl_xor(tm, 32));
        float mn = fmaxf(m_, tm);
        float al = __expf(m_ - mn);
        m_ = mn;
        float p0 = __expf(s0[0]-mn), p1 = __expf(s0[1]-mn), p2 = __expf(s0[2]-mn), p3 = __expf(s0[3]-mn);
        float p4 = __expf(s1[0]-mn), p5 = __expf(s1[1]-mn), p6 = __expf(s1[2]-mn), p7 = __expf(s1[3]-mn);
        float ps = ((p0+p1)+(p2+p3)) + ((p4+p5)+(p6+p7));
        ps += __shfl_xor(ps, 16);
        ps += __shfl_xor(ps, 32);
        l_ = l_ * al + ps;

        // rescale acc (acc rows are q = 4g+reg -> fetch al from lane q)
        #pragma unroll
        for (int j = 0; j < 4; ++j) {
            float alr = __shfl(al, 4 * g + j);
            acc0[j] *= alr;
            acc1[j] *= alr;
        }

        // ---- P -> bf16 A-fragment (in-lane, no transpose) ----
        short8 pf;
        pf[0]=f2bf(p0); pf[1]=f2bf(p1); pf[2]=f2bf(p2); pf[3]=f2bf(p3);
        pf[4]=f2bf(p4); pf[5]=f2bf(p5); pf[6]=f2bf(p6); pf[7]=f2bf(p7);

        // ---- PV: B-fragment slots follow same key permutation ----
        short4 va  = *(const short4*)&VT[l15][4 * g];
        short4 vb2 = *(const short4*)&VT[l15][16 + 4 * g];
        short4 vc  = *(const short4*)&VT[16 + l15][4 * g];
        short4 vd  = *(const short4*)&VT[16 + l15][16 + 4 * g];
        short8 vf0, vf1;
        vf0[0]=va.x;  vf0[1]=va.y;  vf0[2]=va.z;  vf0[3]=va.w;
        vf0[4]=vb2.x; vf0[5]=vb2.y; vf0[6]=vb2.z; vf0[7]=vb2.w;
        vf1[0]=vc.x;  vf1[1]=vc.y;  vf1[2]=vc.z;  vf1[3]=vc.w;
        vf1[4]=vd.x;  vf1[5]=vd.y;  vf1[6]=vd.z;  vf1[7]=vd.w;
        acc0 = __builtin_amdgcn_mfma_f32_16x16x32_bf16(pf, vf0, acc0, 0, 0, 0);
        acc1 = __builtin_amdgcn_mfma_f32_16x16x32_bf16(pf, vf1, acc1, 0, 0, 0);
    }

    // ---- epilogue ----
    float linv = 1.f / l_;
    #pragma unroll
    for (int j = 0; j < 4; ++j) {
        float li = __shfl(linv, 4 * g + j);
        int qrow = q0 + 4 * g + j;
        if (qrow < Q) {
            float* op = ob + (size_t)(b * Q + qrow) * C + h * HD;
            op[l15]      = acc0[j] * li;
            op[16 + l15] = acc1[j] * li;
        }
    }
    #undef LOAD_TILE
}

extern "C" void kernel_launch(void* const* d_in, const int* in_sizes, int n_in,
                              void* d_out, int out_size, void* d_ws, size_t ws_size,
                              hipStream_t stream) {
    const float* f0   = (const float*)d_in[0];
    const float* f1   = (const float*)d_in[1];
    const float* refs = (const float*)d_in[2];
    const float* intr = (const float*)d_in[3];
    const float* extr = (const float*)d_in[4];
    const float* qin  = (const float*)d_in[5];
    const float* Wq   = (const float*)d_in[6];
    const float* bq   = (const float*)d_in[7];
    const float* Wk   = (const float*)d_in[8];
    const float* bk   = (const float*)d_in[9];
    const float* Wv   = (const float*)d_in[10];
    const float* bv   = (const float*)d_in[11];
    const float* Wo   = (const float*)d_in[12];
    const float* bo   = (const float*)d_in[13];

    float* ws      = (float*)d_ws;
    float* sampled = ws;                  // 460800
    float* qbuf    = sampled + 460800;
    float* kbuf    = qbuf    + 460800;
    float* vbuf    = kbuf    + 460800;
    float* obuf    = vbuf    + 460800;
    float* WqT     = obuf    + 460800;    // 65536 each
    float* WkT     = WqT + 65536;
    float* WvT     = WkT + 65536;
    float* WoT     = WvT + 65536;
    float* out     = (float*)d_out;

    wtrans4<<<256, 256, 0, stream>>>(Wq, Wk, Wv, Wo, WqT, WkT, WvT, WoT);

    sampler_kernel<<<B * Q, 256, 0, stream>>>(f0, f1, refs, intr, extr, sampled);

    dim3 ggrid((M_ROWS + 63) / 64, C / 64, 3);
    gemm_qkv<<<ggrid, 256, 0, stream>>>(qin, sampled, WqT, WkT, WvT,
                                        bq, bk, bv, qbuf, kbuf, vbuf);

    dim3 agrid((Q + 31) / 32, NH, B);
    attn_mfma<<<agrid, 128, 0, stream>>>(qbuf, kbuf, vbuf, obuf);

    dim3 ogrid((M_ROWS + 63) / 64, C / 64, 1);
    gemm_one<<<ogrid, 256, 0, stream>>>(obuf, WoT, bo, out);
}

// Round 6
// 83.149 us; speedup vs baseline: 1.7366x; 1.1414x over previous
//
#include <hip/hip_runtime.h>
#include <math.h>

#define B 2
#define V 6
#define C 256
#define Q 900
#define NH 8
#define HD 32
#define RADIUS 2.0f
#define M_ROWS (B * Q)   // 1800
#define NT 29            // ceil(900/32) key tiles

using short8 = __attribute__((ext_vector_type(8))) short;  // 8 bf16
using f32x4  = __attribute__((ext_vector_type(4))) float;

// f32 -> bf16 (RNE), bit pattern in a short
__device__ __forceinline__ short f2bf(float f) {
    union { float f; unsigned u; } x; x.f = f;
    unsigned r = x.u + 0x7fffu + ((x.u >> 16) & 1u);
    return (short)(r >> 16);
}

// keypoints: [0,0,0],[R,0,0],[0,R,0],[-R,0,0]
__device__ __forceinline__ float kpx(int k) { return (k == 1) ? RADIUS : ((k == 3) ? -RADIUS : 0.f); }
__device__ __forceinline__ float kpy(int k) { return (k == 2) ? RADIUS : 0.f; }

__device__ __forceinline__ float tapv(const float* __restrict__ base, float xi, float yi, int W, int H) {
    if (xi < 0.f || xi > (float)(W - 1) || yi < 0.f || yi > (float)(H - 1)) return 0.f;
    int xc = (int)xi, yc = (int)yi;
    return base[yc * W + xc];
}

// One block per (b,q); thread t = channel c.
__global__ __launch_bounds__(256)
void sampler_kernel(const float* __restrict__ f0, const float* __restrict__ f1,
                    const float* __restrict__ refs, const float* __restrict__ intr,
                    const float* __restrict__ extr, float* __restrict__ sampled)
{
    int b = blockIdx.x / Q, q = blockIdx.x % Q;
    int t = threadIdx.x;
    __shared__ float sru[24], srv[24], sval[24];   // u/zs, v/zs, valid

    if (t < 24) {
        int v = t >> 2, kp = t & 3;
        const float* r = refs + (size_t)(b * Q + q) * 3;
        float px = r[0] + kpx(kp), py = r[1] + kpy(kp), pz = r[2];
        const float* E = extr + (size_t)(b * V + v) * 16;
        float cx = E[0] * px + E[1] * py + E[2]  * pz + E[3];
        float cy = E[4] * px + E[5] * py + E[6]  * pz + E[7];
        float cz = E[8] * px + E[9] * py + E[10] * pz + E[11];
        const float* Km = intr + (size_t)(b * V + v) * 9;
        float u = Km[0] * cx + Km[1] * cy + Km[2] * cz;
        float w = Km[3] * cx + Km[4] * cy + Km[5] * cz;
        float z = Km[6] * cx + Km[7] * cy + Km[8] * cz;
        float zs = (fabsf(z) > 1e-6f) ? z : 1e-6f;
        sru[t] = u / zs;
        srv[t] = w / zs;
        sval[t] = (z > 0.f) ? 1.f : 0.f;
    }
    __syncthreads();

    float cnt = 0.f;
    #pragma unroll
    for (int i = 0; i < 24; ++i) cnt += sval[i];
    cnt = fmaxf(cnt, 1.f);
    float icnt = 1.f / cnt;

    float acc_total = 0.f;
    #pragma unroll
    for (int lvl = 0; lvl < 2; ++lvl) {
        const int H = lvl ? 32 : 64;
        const int W = lvl ? 88 : 176;
        const int HW = H * W;
        const float* fm = lvl ? f1 : f0;

        float accl = 0.f;
        for (int i = 0; i < 24; ++i) {
            if (sval[i] == 0.f) continue;
            int v = i >> 2;
            float gx = 2.f * sru[i] / (float)(W - 1) - 1.f;
            float gy = 2.f * srv[i] / (float)(H - 1) - 1.f;
            float x = (gx + 1.f) * 0.5f * (float)(W - 1);
            float y = (gy + 1.f) * 0.5f * (float)(H - 1);
            float x0 = floorf(x), y0 = floorf(y);
            float wx1 = x - x0, wx0 = 1.f - wx1;
            float wy1 = y - y0, wy0 = 1.f - wy1;
            const float* base = fm + ((size_t)(b * V + v) * C + t) * (size_t)HW;
            accl += tapv(base, x0,       y0,       W, H) * (wx0 * wy0)
                  + tapv(base, x0 + 1.f, y0,       W, H) * (wx1 * wy0)
                  + tapv(base, x0,       y0 + 1.f, W, H) * (wx0 * wy1)
                  + tapv(base, x0 + 1.f, y0 + 1.f, W, H) * (wx1 * wy1);
        }
        acc_total += accl * icnt;
    }
    sampled[(size_t)(b * Q + q) * C + t] = acc_total * 0.5f;
}

// Pack 4 weight matrices (W[n][k] fp32) into bf16 B-fragment order for
// mfma_f32_16x16x32_bf16: P[((ks*16 + nt)*64 + lane)*8 + j] = bf16(W[n][k])
// with n = nt*16 + (lane&15), k = ks*32 + 8*(lane>>4) + j.
__global__ __launch_bounds__(256)
void wpack4(const float* __restrict__ W0, const float* __restrict__ W1,
            const float* __restrict__ W2, const float* __restrict__ W3,
            short* __restrict__ P0, short* __restrict__ P1,
            short* __restrict__ P2, short* __restrict__ P3)
{
    int gid = blockIdx.x * 256 + threadIdx.x;   // 32768 total
    int mat = gid >> 13;
    int rem = gid & 8191;
    int ks = rem >> 10;          // 0..7
    int nt = (rem >> 6) & 15;    // 0..15
    int lane = rem & 63;
    const float* W = (mat == 0) ? W0 : (mat == 1) ? W1 : (mat == 2) ? W2 : W3;
    short* P = (mat == 0) ? P0 : (mat == 1) ? P1 : (mat == 2) ? P2 : P3;
    int n = nt * 16 + (lane & 15);
    int k0 = ks * 32 + 8 * (lane >> 4);
    float4 a = *(const float4*)(W + (size_t)n * C + k0);
    float4 b = *(const float4*)(W + (size_t)n * C + k0 + 4);
    short8 s;
    s[0] = f2bf(a.x); s[1] = f2bf(a.y); s[2] = f2bf(a.z); s[3] = f2bf(a.w);
    s[4] = f2bf(b.x); s[5] = f2bf(b.y); s[6] = f2bf(b.z); s[7] = f2bf(b.w);
    *(short8*)(P + (size_t)((ks * 16 + nt) * 64 + lane) * 8) = s;
}

// MFMA GEMM: Y[m][n] = sum_k A[m][k]*W[n][k] + bias[n].
// Block = 256 threads = 4 waves. BM=64 (wave w: rows m0+16w..+15), BN=64
// (4 col-tiles of 16), K=256 = 8 MFMA steps. A staged once to LDS as bf16.
__device__ __forceinline__ void mgemm_body(const float* __restrict__ A,
                                           const short* __restrict__ Wp,
                                           const float* __restrict__ bias,
                                           float* __restrict__ Y,
                                           int m0, int n0t)
{
    __shared__ __align__(16) short As[64][264];   // row pitch 264 shorts (16B-aligned rows)
    const int tid = threadIdx.x;
    const int lane = tid & 63, w = tid >> 6;
    const int l15 = lane & 15, g = lane >> 4;

    // ---- stage A tile (fp32 -> bf16), coalesced float4 reads ----
    {
        int r = tid & 63, part = tid >> 6;   // part covers k = part*64..+63
        int gm = m0 + r;
        #pragma unroll
        for (int c = 0; c < 8; ++c) {
            int k = part * 64 + c * 8;
            float4 x = make_float4(0.f, 0.f, 0.f, 0.f);
            float4 y = make_float4(0.f, 0.f, 0.f, 0.f);
            if (gm < M_ROWS) {
                x = *(const float4*)(A + (size_t)gm * C + k);
                y = *(const float4*)(A + (size_t)gm * C + k + 4);
            }
            short8 s;
            s[0] = f2bf(x.x); s[1] = f2bf(x.y); s[2] = f2bf(x.z); s[3] = f2bf(x.w);
            s[4] = f2bf(y.x); s[5] = f2bf(y.y); s[6] = f2bf(y.z); s[7] = f2bf(y.w);
            *(short8*)&As[r][k] = s;
        }
    }
    __syncthreads();

    f32x4 acc[4];
    #pragma unroll
    for (int c = 0; c < 4; ++c) acc[c] = (f32x4){0.f, 0.f, 0.f, 0.f};

    #pragma unroll
    for (int ks = 0; ks < 8; ++ks) {
        short8 af = *(const short8*)&As[16 * w + l15][ks * 32 + 8 * g];
        #pragma unroll
        for (int c = 0; c < 4; ++c) {
            int nt = n0t * 4 + c;
            short8 bf = *(const short8*)(Wp + (size_t)((ks * 16 + nt) * 64 + lane) * 8);
            acc[c] = __builtin_amdgcn_mfma_f32_16x16x32_bf16(af, bf, acc[c], 0, 0, 0);
        }
    }

    // ---- epilogue: bias + store (C/D: col=lane&15, row=4*(lane>>4)+reg) ----
    #pragma unroll
    for (int c = 0; c < 4; ++c) {
        int n = n0t * 64 + c * 16 + l15;
        float bv = bias[n];
        #pragma unroll
        for (int j = 0; j < 4; ++j) {
            int gm = m0 + 16 * w + 4 * g + j;
            if (gm < M_ROWS) Y[(size_t)gm * C + n] = acc[c][j] + bv;
        }
    }
}

__global__ __launch_bounds__(256)
void gemm_qkv_mfma(const float* __restrict__ Xq, const float* __restrict__ Xs,
                   const short* __restrict__ Pq, const short* __restrict__ Pk,
                   const short* __restrict__ Pv,
                   const float* __restrict__ bq, const float* __restrict__ bk,
                   const float* __restrict__ bv,
                   float* __restrict__ Yq, float* __restrict__ Yk, float* __restrict__ Yv)
{
    int z = blockIdx.z;
    const float* A    = (z == 0) ? Xq : Xs;
    const short* Wp   = (z == 0) ? Pq : (z == 1) ? Pk : Pv;
    const float* bias = (z == 0) ? bq : (z == 1) ? bk : bv;
    float* Y          = (z == 0) ? Yq : (z == 1) ? Yk : Yv;
    mgemm_body(A, Wp, bias, Y, blockIdx.x * 64, blockIdx.y);
}

__global__ __launch_bounds__(256)
void gemm_o_mfma(const float* __restrict__ A, const short* __restrict__ Wp,
                 const float* __restrict__ bias, float* __restrict__ Y)
{
    mgemm_body(A, Wp, bias, Y, blockIdx.x * 64, blockIdx.y);
}

// MFMA flash attention (unchanged from round 5).
__global__ __launch_bounds__(128)
void attn_mfma(const float* __restrict__ qb, const float* __restrict__ kb,
               const float* __restrict__ vb, float* __restrict__ ob)
{
    __shared__ __align__(16) short Ks[32][40];   // [key][dim], padded
    __shared__ __align__(16) short VT[32][36];   // [dim][key], padded

    const int tid = threadIdx.x;
    const int lane = tid & 63;
    const int w = tid >> 6;
    const int l15 = lane & 15, g = lane >> 4;
    const int b = blockIdx.z, h = blockIdx.y;
    const int q0 = blockIdx.x * 32 + w * 16;

    short8 qf;
    {
        const float sc = 0.17677669529663687f; // 1/sqrt(32)
        int qrow = q0 + l15;
        float4 a = make_float4(0.f,0.f,0.f,0.f), c2 = make_float4(0.f,0.f,0.f,0.f);
        if (qrow < Q) {
            const float* p = qb + (size_t)(b * Q + qrow) * C + h * HD + 8 * g;
            a  = *(const float4*)p;
            c2 = *(const float4*)(p + 4);
        }
        qf[0]=f2bf(a.x*sc);  qf[1]=f2bf(a.y*sc);  qf[2]=f2bf(a.z*sc);  qf[3]=f2bf(a.w*sc);
        qf[4]=f2bf(c2.x*sc); qf[5]=f2bf(c2.y*sc); qf[6]=f2bf(c2.z*sc); qf[7]=f2bf(c2.w*sc);
    }

    float m_ = -1e30f, l_ = 0.f;
    f32x4 acc0 = {0.f,0.f,0.f,0.f}, acc1 = {0.f,0.f,0.f,0.f};
    const f32x4 z4 = {0.f,0.f,0.f,0.f};

    const int keyA = tid >> 3,        ccA = tid & 7;
    const int keyB = (128 + tid) >> 3, ccB = tid & 7;
    float4 kregA, vregA, kregB, vregB;

    #define LOAD_TILE(t)                                                        \
    {                                                                           \
        int gkA = (t) * 32 + keyA, gkB = (t) * 32 + keyB;                       \
        if (gkA < Q) {                                                          \
            const float* kp = kb + (size_t)(b*Q+gkA)*C + h*HD + 4*ccA;          \
            const float* vp = vb + (size_t)(b*Q+gkA)*C + h*HD + 4*ccA;          \
            kregA = *(const float4*)kp; vregA = *(const float4*)vp;             \
        } else { kregA = make_float4(0.f,0.f,0.f,0.f); vregA = kregA; }         \
        if (gkB < Q) {                                                          \
            const float* kp = kb + (size_t)(b*Q+gkB)*C + h*HD + 4*ccB;          \
            const float* vp = vb + (size_t)(b*Q+gkB)*C + h*HD + 4*ccB;          \
            kregB = *(const float4*)kp; vregB = *(const float4*)vp;             \
        } else { kregB = make_float4(0.f,0.f,0.f,0.f); vregB = kregB; }         \
    }

    LOAD_TILE(0);

    for (int t = 0; t < NT; ++t) {
        __syncthreads();
        {
            short4 ks;
            ks.x = f2bf(kregA.x); ks.y = f2bf(kregA.y); ks.z = f2bf(kregA.z); ks.w = f2bf(kregA.w);
            *(short4*)&Ks[keyA][4 * ccA] = ks;
            VT[4*ccA+0][keyA] = f2bf(vregA.x);
            VT[4*ccA+1][keyA] = f2bf(vregA.y);
            VT[4*ccA+2][keyA] = f2bf(vregA.z);
            VT[4*ccA+3][keyA] = f2bf(vregA.w);
            ks.x = f2bf(kregB.x); ks.y = f2bf(kregB.y); ks.z = f2bf(kregB.z); ks.w = f2bf(kregB.w);
            *(short4*)&Ks[keyB][4 * ccB] = ks;
            VT[4*ccB+0][keyB] = f2bf(vregB.x);
            VT[4*ccB+1][keyB] = f2bf(vregB.y);
            VT[4*ccB+2][keyB] = f2bf(vregB.z);
            VT[4*ccB+3][keyB] = f2bf(vregB.w);
        }
        __syncthreads();

        if (t + 1 < NT) LOAD_TILE(t + 1);

        short8 kf0 = *(const short8*)&Ks[l15][8 * g];
        short8 kf1 = *(const short8*)&Ks[16 + l15][8 * g];
        f32x4 s0 = __builtin_amdgcn_mfma_f32_16x16x32_bf16(kf0, qf, z4, 0, 0, 0);
        f32x4 s1 = __builtin_amdgcn_mfma_f32_16x16x32_bf16(kf1, qf, z4, 0, 0, 0);

        const int kbase = t * 32;
        if (kbase + 32 > Q) {
            #pragma unroll
            for (int j = 0; j < 4; ++j) {
                if (kbase + 4 * g + j      >= Q) s0[j] = -1e30f;
                if (kbase + 16 + 4 * g + j >= Q) s1[j] = -1e30f;
            }
        }

        float tm = fmaxf(fmaxf(fmaxf(s0[0], s0[1]), fmaxf(s0[2], s0[3])),
                         fmaxf(fmaxf(s1[0], s1[1]), fmaxf(s1[2], s1[3])));
        tm = fmaxf(tm, __shfl_xor(tm, 16));
        tm = fmaxf(tm, __shfl_xor(tm, 32));
        float mn = fmaxf(m_, tm);
        float al = __expf(m_ - mn);
        m_ = mn;
        float p0 = __expf(s0[0]-mn), p1 = __expf(s0[1]-mn), p2 = __expf(s0[2]-mn), p3 = __expf(s0[3]-mn);
        float p4 = __expf(s1[0]-mn), p5 = __expf(s1[1]-mn), p6 = __expf(s1[2]-mn), p7 = __expf(s1[3]-mn);
        float ps = ((p0+p1)+(p2+p3)) + ((p4+p5)+(p6+p7));
        ps += __shfl_xor(ps, 16);
        ps += __shfl_xor(ps, 32);
        l_ = l_ * al + ps;

        #pragma unroll
        for (int j = 0; j < 4; ++j) {
            float alr = __shfl(al, 4 * g + j);
            acc0[j] *= alr;
            acc1[j] *= alr;
        }

        short8 pf;
        pf[0]=f2bf(p0); pf[1]=f2bf(p1); pf[2]=f2bf(p2); pf[3]=f2bf(p3);
        pf[4]=f2bf(p4); pf[5]=f2bf(p5); pf[6]=f2bf(p6); pf[7]=f2bf(p7);

        short4 va  = *(const short4*)&VT[l15][4 * g];
        short4 vb2 = *(const short4*)&VT[l15][16 + 4 * g];
        short4 vc  = *(const short4*)&VT[16 + l15][4 * g];
        short4 vd  = *(const short4*)&VT[16 + l15][16 + 4 * g];
        short8 vf0, vf1;
        vf0[0]=va.x;  vf0[1]=va.y;  vf0[2]=va.z;  vf0[3]=va.w;
        vf0[4]=vb2.x; vf0[5]=vb2.y; vf0[6]=vb2.z; vf0[7]=vb2.w;
        vf1[0]=vc.x;  vf1[1]=vc.y;  vf1[2]=vc.z;  vf1[3]=vc.w;
        vf1[4]=vd.x;  vf1[5]=vd.y;  vf1[6]=vd.z;  vf1[7]=vd.w;
        acc0 = __builtin_amdgcn_mfma_f32_16x16x32_bf16(pf, vf0, acc0, 0, 0, 0);
        acc1 = __builtin_amdgcn_mfma_f32_16x16x32_bf16(pf, vf1, acc1, 0, 0, 0);
    }

    float linv = 1.f / l_;
    #pragma unroll
    for (int j = 0; j < 4; ++j) {
        float li = __shfl(linv, 4 * g + j);
        int qrow = q0 + 4 * g + j;
        if (qrow < Q) {
            float* op = ob + (size_t)(b * Q + qrow) * C + h * HD;
            op[l15]      = acc0[j] * li;
            op[16 + l15] = acc1[j] * li;
        }
    }
    #undef LOAD_TILE
}

extern "C" void kernel_launch(void* const* d_in, const int* in_sizes, int n_in,
                              void* d_out, int out_size, void* d_ws, size_t ws_size,
                              hipStream_t stream) {
    const float* f0   = (const float*)d_in[0];
    const float* f1   = (const float*)d_in[1];
    const float* refs = (const float*)d_in[2];
    const float* intr = (const float*)d_in[3];
    const float* extr = (const float*)d_in[4];
    const float* qin  = (const float*)d_in[5];
    const float* Wq   = (const float*)d_in[6];
    const float* bq   = (const float*)d_in[7];
    const float* Wk   = (const float*)d_in[8];
    const float* bk   = (const float*)d_in[9];
    const float* Wv   = (const float*)d_in[10];
    const float* bv   = (const float*)d_in[11];
    const float* Wo   = (const float*)d_in[12];
    const float* bo   = (const float*)d_in[13];

    float* ws      = (float*)d_ws;
    float* sampled = ws;                  // 460800 each
    float* qbuf    = sampled + 460800;
    float* kbuf    = qbuf    + 460800;
    float* vbuf    = kbuf    + 460800;
    float* obuf    = vbuf    + 460800;
    short* Pq      = (short*)(obuf + 460800);   // 65536 bf16 each
    short* Pk      = Pq + 65536;
    short* Pv      = Pk + 65536;
    short* Po      = Pv + 65536;
    float* out     = (float*)d_out;

    wpack4<<<128, 256, 0, stream>>>(Wq, Wk, Wv, Wo, Pq, Pk, Pv, Po);

    sampler_kernel<<<B * Q, 256, 0, stream>>>(f0, f1, refs, intr, extr, sampled);

    dim3 ggrid((M_ROWS + 63) / 64, C / 64, 3);
    gemm_qkv_mfma<<<ggrid, 256, 0, stream>>>(qin, sampled, Pq, Pk, Pv,
                                             bq, bk, bv, qbuf, kbuf, vbuf);

    dim3 agrid((Q + 31) / 32, NH, B);
    attn_mfma<<<agrid, 128, 0, stream>>>(qbuf, kbuf, vbuf, obuf);

    dim3 ogrid((M_ROWS + 63) / 64, C / 64, 1);
    gemm_o_mfma<<<ogrid, 256, 0, stream>>>(obuf, Po, bo, out);
}

// Round 7
// 67.631 us; speedup vs baseline: 2.1350x; 1.2295x over previous
//
#include <hip/hip_runtime.h>
#include <math.h>

#define B 2
#define V 6
#define C 256
#define Q 900
#define NH 8
#define HD 32
#define RADIUS 2.0f
#define M_ROWS (B * Q)   // 1800
#define NT 29            // ceil(900/32) key tiles
#define SPLITS 4
#define TPS 8            // tiles per split (last split gets 5)

using short8 = __attribute__((ext_vector_type(8))) short;  // 8 bf16
using f32x4  = __attribute__((ext_vector_type(4))) float;

// f32 -> bf16 (RNE), bit pattern in a short
__device__ __forceinline__ short f2bf(float f) {
    union { float f; unsigned u; } x; x.f = f;
    unsigned r = x.u + 0x7fffu + ((x.u >> 16) & 1u);
    return (short)(r >> 16);
}

// keypoints: [0,0,0],[R,0,0],[0,R,0],[-R,0,0]
__device__ __forceinline__ float kpx(int k) { return (k == 1) ? RADIUS : ((k == 3) ? -RADIUS : 0.f); }
__device__ __forceinline__ float kpy(int k) { return (k == 2) ? RADIUS : 0.f; }

__device__ __forceinline__ float tapv(const float* __restrict__ base, float xi, float yi, int W, int H) {
    if (xi < 0.f || xi > (float)(W - 1) || yi < 0.f || yi > (float)(H - 1)) return 0.f;
    int xc = (int)xi, yc = (int)yi;
    return base[yc * W + xc];
}

// One block per (b,q); thread t = channel c. All per-(point,level) grid
// arithmetic (incl. the 2 fp32 divides) hoisted into a 48-thread precompute.
__global__ __launch_bounds__(256)
void sampler_kernel(const float* __restrict__ f0, const float* __restrict__ f1,
                    const float* __restrict__ refs, const float* __restrict__ intr,
                    const float* __restrict__ extr, float* __restrict__ sampled)
{
    int b = blockIdx.x / Q, q = blockIdx.x % Q;
    int t = threadIdx.x;
    __shared__ float sx0[2][24], sy0[2][24], swx1[2][24], swy1[2][24];
    __shared__ float sval[24];

    if (t < 48) {
        int lvl = t / 24, pt = t % 24;
        int v = pt >> 2, kp = pt & 3;
        const float* r = refs + (size_t)(b * Q + q) * 3;
        float px = r[0] + kpx(kp), py = r[1] + kpy(kp), pz = r[2];
        const float* E = extr + (size_t)(b * V + v) * 16;
        float cx = E[0] * px + E[1] * py + E[2]  * pz + E[3];
        float cy = E[4] * px + E[5] * py + E[6]  * pz + E[7];
        float cz = E[8] * px + E[9] * py + E[10] * pz + E[11];
        const float* Km = intr + (size_t)(b * V + v) * 9;
        float u = Km[0] * cx + Km[1] * cy + Km[2] * cz;
        float w = Km[3] * cx + Km[4] * cy + Km[5] * cz;
        float z = Km[6] * cx + Km[7] * cy + Km[8] * cz;
        float zs = (fabsf(z) > 1e-6f) ? z : 1e-6f;
        float ru = u / zs, rv = w / zs;
        const float Wf = lvl ? 87.f : 175.f;   // W-1
        const float Hf = lvl ? 31.f : 63.f;    // H-1
        float gx = 2.f * ru / Wf - 1.f;
        float gy = 2.f * rv / Hf - 1.f;
        float x = (gx + 1.f) * 0.5f * Wf;
        float y = (gy + 1.f) * 0.5f * Hf;
        float x0 = floorf(x), y0 = floorf(y);
        sx0[lvl][pt] = x0;  sy0[lvl][pt] = y0;
        swx1[lvl][pt] = x - x0;  swy1[lvl][pt] = y - y0;
        if (lvl == 0) sval[pt] = (z > 0.f) ? 1.f : 0.f;
    }
    __syncthreads();

    float cnt = 0.f;
    #pragma unroll
    for (int i = 0; i < 24; ++i) cnt += sval[i];
    cnt = fmaxf(cnt, 1.f);
    float icnt = 1.f / cnt;

    float acc_total = 0.f;
    #pragma unroll
    for (int lvl = 0; lvl < 2; ++lvl) {
        const int H = lvl ? 32 : 64;
        const int W = lvl ? 88 : 176;
        const int HW = H * W;
        const float* fm = lvl ? f1 : f0;

        float accl = 0.f;
        for (int i = 0; i < 24; ++i) {
            if (sval[i] == 0.f) continue;
            int v = i >> 2;
            float x0 = sx0[lvl][i], y0 = sy0[lvl][i];
            float wx1 = swx1[lvl][i], wy1 = swy1[lvl][i];
            float wx0 = 1.f - wx1, wy0 = 1.f - wy1;
            const float* base = fm + ((size_t)(b * V + v) * C + t) * (size_t)HW;
            accl += tapv(base, x0,       y0,       W, H) * (wx0 * wy0)
                  + tapv(base, x0 + 1.f, y0,       W, H) * (wx1 * wy0)
                  + tapv(base, x0,       y0 + 1.f, W, H) * (wx0 * wy1)
                  + tapv(base, x0 + 1.f, y0 + 1.f, W, H) * (wx1 * wy1);
        }
        acc_total += accl * icnt;
    }
    sampled[(size_t)(b * Q + q) * C + t] = acc_total * 0.5f;
}

// Pack 4 weight matrices (W[n][k] fp32) into bf16 B-fragment order.
__global__ __launch_bounds__(256)
void wpack4(const float* __restrict__ W0, const float* __restrict__ W1,
            const float* __restrict__ W2, const float* __restrict__ W3,
            short* __restrict__ P0, short* __restrict__ P1,
            short* __restrict__ P2, short* __restrict__ P3)
{
    int gid = blockIdx.x * 256 + threadIdx.x;   // 32768 total
    int mat = gid >> 13;
    int rem = gid & 8191;
    int ks = rem >> 10;          // 0..7
    int nt = (rem >> 6) & 15;    // 0..15
    int lane = rem & 63;
    const float* W = (mat == 0) ? W0 : (mat == 1) ? W1 : (mat == 2) ? W2 : W3;
    short* P = (mat == 0) ? P0 : (mat == 1) ? P1 : (mat == 2) ? P2 : P3;
    int n = nt * 16 + (lane & 15);
    int k0 = ks * 32 + 8 * (lane >> 4);
    float4 a = *(const float4*)(W + (size_t)n * C + k0);
    float4 b = *(const float4*)(W + (size_t)n * C + k0 + 4);
    short8 s;
    s[0] = f2bf(a.x); s[1] = f2bf(a.y); s[2] = f2bf(a.z); s[3] = f2bf(a.w);
    s[4] = f2bf(b.x); s[5] = f2bf(b.y); s[6] = f2bf(b.z); s[7] = f2bf(b.w);
    *(short8*)(P + (size_t)((ks * 16 + nt) * 64 + lane) * 8) = s;
}

// MFMA GEMM: Y[m][n] = sum_k A[m][k]*W[n][k] + bias[n].
__device__ __forceinline__ void mgemm_body(const float* __restrict__ A,
                                           const short* __restrict__ Wp,
                                           const float* __restrict__ bias,
                                           float* __restrict__ Y,
                                           int m0, int n0t)
{
    __shared__ __align__(16) short As[64][264];
    const int tid = threadIdx.x;
    const int lane = tid & 63, w = tid >> 6;
    const int l15 = lane & 15, g = lane >> 4;

    {
        int r = tid & 63, part = tid >> 6;
        int gm = m0 + r;
        #pragma unroll
        for (int c = 0; c < 8; ++c) {
            int k = part * 64 + c * 8;
            float4 x = make_float4(0.f, 0.f, 0.f, 0.f);
            float4 y = make_float4(0.f, 0.f, 0.f, 0.f);
            if (gm < M_ROWS) {
                x = *(const float4*)(A + (size_t)gm * C + k);
                y = *(const float4*)(A + (size_t)gm * C + k + 4);
            }
            short8 s;
            s[0] = f2bf(x.x); s[1] = f2bf(x.y); s[2] = f2bf(x.z); s[3] = f2bf(x.w);
            s[4] = f2bf(y.x); s[5] = f2bf(y.y); s[6] = f2bf(y.z); s[7] = f2bf(y.w);
            *(short8*)&As[r][k] = s;
        }
    }
    __syncthreads();

    f32x4 acc[4];
    #pragma unroll
    for (int c = 0; c < 4; ++c) acc[c] = (f32x4){0.f, 0.f, 0.f, 0.f};

    #pragma unroll
    for (int ks = 0; ks < 8; ++ks) {
        short8 af = *(const short8*)&As[16 * w + l15][ks * 32 + 8 * g];
        #pragma unroll
        for (int c = 0; c < 4; ++c) {
            int nt = n0t * 4 + c;
            short8 bf = *(const short8*)(Wp + (size_t)((ks * 16 + nt) * 64 + lane) * 8);
            acc[c] = __builtin_amdgcn_mfma_f32_16x16x32_bf16(af, bf, acc[c], 0, 0, 0);
        }
    }

    #pragma unroll
    for (int c = 0; c < 4; ++c) {
        int n = n0t * 64 + c * 16 + l15;
        float bv = bias[n];
        #pragma unroll
        for (int j = 0; j < 4; ++j) {
            int gm = m0 + 16 * w + 4 * g + j;
            if (gm < M_ROWS) Y[(size_t)gm * C + n] = acc[c][j] + bv;
        }
    }
}

__global__ __launch_bounds__(256)
void gemm_qkv_mfma(const float* __restrict__ Xq, const float* __restrict__ Xs,
                   const short* __restrict__ Pq, const short* __restrict__ Pk,
                   const short* __restrict__ Pv,
                   const float* __restrict__ bq, const float* __restrict__ bk,
                   const float* __restrict__ bv,
                   float* __restrict__ Yq, float* __restrict__ Yk, float* __restrict__ Yv)
{
    int z = blockIdx.z;
    const float* A    = (z == 0) ? Xq : Xs;
    const short* Wp   = (z == 0) ? Pq : (z == 1) ? Pk : Pv;
    const float* bias = (z == 0) ? bq : (z == 1) ? bk : bv;
    float* Y          = (z == 0) ? Yq : (z == 1) ? Yk : Yv;
    mgemm_body(A, Wp, bias, Y, blockIdx.x * 64, blockIdx.y);
}

__global__ __launch_bounds__(256)
void gemm_o_mfma(const float* __restrict__ A, const short* __restrict__ Wp,
                 const float* __restrict__ bias, float* __restrict__ Y)
{
    mgemm_body(A, Wp, bias, Y, blockIdx.x * 64, blockIdx.y);
}

// Split-K MFMA flash attention. blockIdx.z = b*SPLITS + s; split s covers key
// tiles [s*TPS, min(s*TPS+TPS, NT)). Double-buffered LDS -> 1 barrier/tile.
// Writes unnormalized partial O and per-row (m,l) for the merge kernel.
__global__ __launch_bounds__(128)
void attn_mfma_split(const float* __restrict__ qb, const float* __restrict__ kb,
                     const float* __restrict__ vb,
                     float* __restrict__ Opart, float2* __restrict__ ml)
{
    __shared__ __align__(16) short Ks[2][32][40];   // [buf][key][dim]
    __shared__ __align__(16) short VT[2][32][36];   // [buf][dim][key]

    const int tid = threadIdx.x;
    const int lane = tid & 63;
    const int w = tid >> 6;
    const int l15 = lane & 15, g = lane >> 4;
    const int bz = blockIdx.z;
    const int b = bz >> 2, s = bz & 3;
    const int h = blockIdx.y;
    const int q0 = blockIdx.x * 32 + w * 16;
    const int t0 = s * TPS;
    const int t1 = (t0 + TPS < NT) ? (t0 + TPS) : NT;

    // ---- Q fragment (scaled, bf16) ----
    short8 qf;
    {
        const float sc = 0.17677669529663687f; // 1/sqrt(32)
        int qrow = q0 + l15;
        float4 a = make_float4(0.f,0.f,0.f,0.f), c2 = make_float4(0.f,0.f,0.f,0.f);
        if (qrow < Q) {
            const float* p = qb + (size_t)(b * Q + qrow) * C + h * HD + 8 * g;
            a  = *(const float4*)p;
            c2 = *(const float4*)(p + 4);
        }
        qf[0]=f2bf(a.x*sc);  qf[1]=f2bf(a.y*sc);  qf[2]=f2bf(a.z*sc);  qf[3]=f2bf(a.w*sc);
        qf[4]=f2bf(c2.x*sc); qf[5]=f2bf(c2.y*sc); qf[6]=f2bf(c2.z*sc); qf[7]=f2bf(c2.w*sc);
    }

    float m_ = -1e30f, l_ = 0.f;
    f32x4 acc0 = {0.f,0.f,0.f,0.f}, acc1 = {0.f,0.f,0.f,0.f};
    const f32x4 z4 = {0.f,0.f,0.f,0.f};

    const int keyA = tid >> 3,        ccA = tid & 7;
    const int keyB = (128 + tid) >> 3, ccB = tid & 7;
    float4 kregA, vregA, kregB, vregB;

    #define LOAD_TILE(t)                                                        \
    {                                                                           \
        int gkA = (t) * 32 + keyA, gkB = (t) * 32 + keyB;                       \
        if (gkA < Q) {                                                          \
            const float* kp = kb + (size_t)(b*Q+gkA)*C + h*HD + 4*ccA;          \
            const float* vp = vb + (size_t)(b*Q+gkA)*C + h*HD + 4*ccA;          \
            kregA = *(const float4*)kp; vregA = *(const float4*)vp;             \
        } else { kregA = make_float4(0.f,0.f,0.f,0.f); vregA = kregA; }         \
        if (gkB < Q) {                                                          \
            const float* kp = kb + (size_t)(b*Q+gkB)*C + h*HD + 4*ccB;          \
            const float* vp = vb + (size_t)(b*Q+gkB)*C + h*HD + 4*ccB;          \
            kregB = *(const float4*)kp; vregB = *(const float4*)vp;             \
        } else { kregB = make_float4(0.f,0.f,0.f,0.f); vregB = kregB; }         \
    }

    #define WRITE_LDS(bi)                                                       \
    {                                                                           \
        short4 ks;                                                              \
        ks.x = f2bf(kregA.x); ks.y = f2bf(kregA.y); ks.z = f2bf(kregA.z); ks.w = f2bf(kregA.w); \
        *(short4*)&Ks[bi][keyA][4 * ccA] = ks;                                  \
        VT[bi][4*ccA+0][keyA] = f2bf(vregA.x);                                  \
        VT[bi][4*ccA+1][keyA] = f2bf(vregA.y);                                  \
        VT[bi][4*ccA+2][keyA] = f2bf(vregA.z);                                  \
        VT[bi][4*ccA+3][keyA] = f2bf(vregA.w);                                  \
        ks.x = f2bf(kregB.x); ks.y = f2bf(kregB.y); ks.z = f2bf(kregB.z); ks.w = f2bf(kregB.w); \
        *(short4*)&Ks[bi][keyB][4 * ccB] = ks;                                  \
        VT[bi][4*ccB+0][keyB] = f2bf(vregB.x);                                  \
        VT[bi][4*ccB+1][keyB] = f2bf(vregB.y);                                  \
        VT[bi][4*ccB+2][keyB] = f2bf(vregB.z);                                  \
        VT[bi][4*ccB+3][keyB] = f2bf(vregB.w);                                  \
    }

    LOAD_TILE(t0);
    WRITE_LDS(0);
    __syncthreads();

    for (int t = t0; t < t1; ++t) {
        const int buf = (t - t0) & 1;
        if (t + 1 < t1) LOAD_TILE(t + 1);

        // ---- QK^T (swapped): S^T[key][q] ----
        short8 kf0 = *(const short8*)&Ks[buf][l15][8 * g];
        short8 kf1 = *(const short8*)&Ks[buf][16 + l15][8 * g];
        f32x4 s0 = __builtin_amdgcn_mfma_f32_16x16x32_bf16(kf0, qf, z4, 0, 0, 0);
        f32x4 s1 = __builtin_amdgcn_mfma_f32_16x16x32_bf16(kf1, qf, z4, 0, 0, 0);

        const int kbase = t * 32;
        if (kbase + 32 > Q) {
            #pragma unroll
            for (int j = 0; j < 4; ++j) {
                if (kbase + 4 * g + j      >= Q) s0[j] = -1e30f;
                if (kbase + 16 + 4 * g + j >= Q) s1[j] = -1e30f;
            }
        }

        // ---- online softmax per q-col (lane&15) ----
        float tm = fmaxf(fmaxf(fmaxf(s0[0], s0[1]), fmaxf(s0[2], s0[3])),
                         fmaxf(fmaxf(s1[0], s1[1]), fmaxf(s1[2], s1[3])));
        tm = fmaxf(tm, __shfl_xor(tm, 16));
        tm = fmaxf(tm, __shfl_xor(tm, 32));
        float mn = fmaxf(m_, tm);
        float al = __expf(m_ - mn);
        m_ = mn;
        float p0 = __expf(s0[0]-mn), p1 = __expf(s0[1]-mn), p2 = __expf(s0[2]-mn), p3 = __expf(s0[3]-mn);
        float p4 = __expf(s1[0]-mn), p5 = __expf(s1[1]-mn), p6 = __expf(s1[2]-mn), p7 = __expf(s1[3]-mn);
        float ps = ((p0+p1)+(p2+p3)) + ((p4+p5)+(p6+p7));
        ps += __shfl_xor(ps, 16);
        ps += __shfl_xor(ps, 32);
        l_ = l_ * al + ps;

        #pragma unroll
        for (int j = 0; j < 4; ++j) {
            float alr = __shfl(al, 4 * g + j);
            acc0[j] *= alr;
            acc1[j] *= alr;
        }

        short8 pf;
        pf[0]=f2bf(p0); pf[1]=f2bf(p1); pf[2]=f2bf(p2); pf[3]=f2bf(p3);
        pf[4]=f2bf(p4); pf[5]=f2bf(p5); pf[6]=f2bf(p6); pf[7]=f2bf(p7);

        short4 va  = *(const short4*)&VT[buf][l15][4 * g];
        short4 vb2 = *(const short4*)&VT[buf][l15][16 + 4 * g];
        short4 vc  = *(const short4*)&VT[buf][16 + l15][4 * g];
        short4 vd  = *(const short4*)&VT[buf][16 + l15][16 + 4 * g];
        short8 vf0, vf1;
        vf0[0]=va.x;  vf0[1]=va.y;  vf0[2]=va.z;  vf0[3]=va.w;
        vf0[4]=vb2.x; vf0[5]=vb2.y; vf0[6]=vb2.z; vf0[7]=vb2.w;
        vf1[0]=vc.x;  vf1[1]=vc.y;  vf1[2]=vc.z;  vf1[3]=vc.w;
        vf1[4]=vd.x;  vf1[5]=vd.y;  vf1[6]=vd.z;  vf1[7]=vd.w;
        acc0 = __builtin_amdgcn_mfma_f32_16x16x32_bf16(pf, vf0, acc0, 0, 0, 0);
        acc1 = __builtin_amdgcn_mfma_f32_16x16x32_bf16(pf, vf1, acc1, 0, 0, 0);

        if (t + 1 < t1) WRITE_LDS(buf ^ 1);
        __syncthreads();
    }

    // ---- epilogue: unnormalized partials + (m,l) ----
    const size_t rowbase = (size_t)((s * B + b) * NH + h) * Q;
    float* op = Opart + rowbase * 32;
    #pragma unroll
    for (int j = 0; j < 4; ++j) {
        int qrow = q0 + 4 * g + j;
        if (qrow < Q) {
            op[(size_t)qrow * 32 + l15]      = acc0[j];
            op[(size_t)qrow * 32 + 16 + l15] = acc1[j];
        }
    }
    if (g == 0 && q0 + l15 < Q) ml[rowbase + q0 + l15] = make_float2(m_, l_);
    #undef LOAD_TILE
    #undef WRITE_LDS
}

// Merge SPLITS partials: standard flash merge, then normalize.
__global__ __launch_bounds__(256)
void attn_merge(const float* __restrict__ Opart, const float2* __restrict__ ml,
                float* __restrict__ ob)
{
    const int RBH = B * NH * Q;   // 14400 rows per split
    int idx = blockIdx.x * 256 + threadIdx.x;   // < 460800
    int d = idx & 31;
    int r = idx >> 5;            // (b*NH + h)*Q + q
    int b = r / (NH * Q);
    int rem = r - b * (NH * Q);
    int h = rem / Q;
    int q = rem - h * Q;

    float m = -1e30f;
    #pragma unroll
    for (int s = 0; s < SPLITS; ++s) m = fmaxf(m, ml[(size_t)s * RBH + r].x);
    float l = 0.f, o = 0.f;
    #pragma unroll
    for (int s = 0; s < SPLITS; ++s) {
        float2 v = ml[(size_t)s * RBH + r];
        float wgt = __expf(v.x - m);
        l += v.y * wgt;
        o += Opart[((size_t)s * RBH + r) * 32 + d] * wgt;
    }
    ob[((size_t)b * Q + q) * C + h * HD + d] = o / l;
}

extern "C" void kernel_launch(void* const* d_in, const int* in_sizes, int n_in,
                              void* d_out, int out_size, void* d_ws, size_t ws_size,
                              hipStream_t stream) {
    const float* f0   = (const float*)d_in[0];
    const float* f1   = (const float*)d_in[1];
    const float* refs = (const float*)d_in[2];
    const float* intr = (const float*)d_in[3];
    const float* extr = (const float*)d_in[4];
    const float* qin  = (const float*)d_in[5];
    const float* Wq   = (const float*)d_in[6];
    const float* bq   = (const float*)d_in[7];
    const float* Wk   = (const float*)d_in[8];
    const float* bk   = (const float*)d_in[9];
    const float* Wv   = (const float*)d_in[10];
    const float* bv   = (const float*)d_in[11];
    const float* Wo   = (const float*)d_in[12];
    const float* bo   = (const float*)d_in[13];

    float* ws      = (float*)d_ws;
    float* sampled = ws;                  // 460800 each
    float* qbuf    = sampled + 460800;
    float* kbuf    = qbuf    + 460800;
    float* vbuf    = kbuf    + 460800;
    float* obuf    = vbuf    + 460800;
    short* Pq      = (short*)(obuf + 460800);   // 65536 bf16 each
    short* Pk      = Pq + 65536;
    short* Pv      = Pk + 65536;
    short* Po      = Pv + 65536;
    float* Opart   = obuf + 460800 + 131072;    // SPLITS*14400*32 = 1,843,200 f32
    float2* ml     = (float2*)(Opart + (size_t)SPLITS * B * NH * Q * 32);
    float* out     = (float*)d_out;

    wpack4<<<128, 256, 0, stream>>>(Wq, Wk, Wv, Wo, Pq, Pk, Pv, Po);

    sampler_kernel<<<B * Q, 256, 0, stream>>>(f0, f1, refs, intr, extr, sampled);

    dim3 ggrid((M_ROWS + 63) / 64, C / 64, 3);
    gemm_qkv_mfma<<<ggrid, 256, 0, stream>>>(qin, sampled, Pq, Pk, Pv,
                                             bq, bk, bv, qbuf, kbuf, vbuf);

    dim3 agrid((Q + 31) / 32, NH, B * SPLITS);
    attn_mfma_split<<<agrid, 128, 0, stream>>>(qbuf, kbuf, vbuf, Opart, ml);

    attn_merge<<<1800, 256, 0, stream>>>(Opart, ml, obuf);

    dim3 ogrid((M_ROWS + 63) / 64, C / 64, 1);
    gemm_o_mfma<<<ogrid, 256, 0, stream>>>(obuf, Po, bo, out);
}

// Round 8
// 62.793 us; speedup vs baseline: 2.2995x; 1.0770x over previous
//
#include <hip/hip_runtime.h>
#include <math.h>

#define B 2
#define V 6
#define C 256
#define Q 900
#define NH 8
#define HD 32
#define RADIUS 2.0f
#define M_ROWS (B * Q)   // 1800
#define NT 29            // ceil(900/32) key tiles
#define SPLITS 4
#define TPS 8            // tiles per split (last split gets 5)
#define RBH (B * NH * Q) // 14400 rows per split

using short8 = __attribute__((ext_vector_type(8))) short;  // 8 bf16
using f32x4  = __attribute__((ext_vector_type(4))) float;

// f32 -> bf16 (RNE), bit pattern in a short
__device__ __forceinline__ short f2bf(float f) {
    union { float f; unsigned u; } x; x.f = f;
    unsigned r = x.u + 0x7fffu + ((x.u >> 16) & 1u);
    return (short)(r >> 16);
}

// keypoints: [0,0,0],[R,0,0],[0,R,0],[-R,0,0]
__device__ __forceinline__ float kpx(int k) { return (k == 1) ? RADIUS : ((k == 3) ? -RADIUS : 0.f); }
__device__ __forceinline__ float kpy(int k) { return (k == 2) ? RADIUS : 0.f; }

// One block per (b,q). Lane pairing: lane = 2*chanslot + xi; the two x-taps of
// a bilinear sample sit in adjacent lanes -> same cache line -> TA merges the
// line requests (halves gather request count vs 1-lane-per-channel).
__global__ __launch_bounds__(256)
void sampler_kernel(const float* __restrict__ f0, const float* __restrict__ f1,
                    const float* __restrict__ refs, const float* __restrict__ intr,
                    const float* __restrict__ extr, float* __restrict__ sampled)
{
    int b = blockIdx.x / Q, q = blockIdx.x % Q;
    int t = threadIdx.x;
    __shared__ float sx0[2][24], sy0[2][24], swx1[2][24], swy1[2][24];
    __shared__ float sval[24];

    if (t < 48) {
        int lvl = t / 24, pt = t % 24;
        int v = pt >> 2, kp = pt & 3;
        const float* r = refs + (size_t)(b * Q + q) * 3;
        float px = r[0] + kpx(kp), py = r[1] + kpy(kp), pz = r[2];
        const float* E = extr + (size_t)(b * V + v) * 16;
        float cx = E[0] * px + E[1] * py + E[2]  * pz + E[3];
        float cy = E[4] * px + E[5] * py + E[6]  * pz + E[7];
        float cz = E[8] * px + E[9] * py + E[10] * pz + E[11];
        const float* Km = intr + (size_t)(b * V + v) * 9;
        float u = Km[0] * cx + Km[1] * cy + Km[2] * cz;
        float w = Km[3] * cx + Km[4] * cy + Km[5] * cz;
        float z = Km[6] * cx + Km[7] * cy + Km[8] * cz;
        float zs = (fabsf(z) > 1e-6f) ? z : 1e-6f;
        float ru = u / zs, rv = w / zs;
        const float Wf = lvl ? 87.f : 175.f;   // W-1
        const float Hf = lvl ? 31.f : 63.f;    // H-1
        float gx = 2.f * ru / Wf - 1.f;
        float gy = 2.f * rv / Hf - 1.f;
        float x = (gx + 1.f) * 0.5f * Wf;
        float y = (gy + 1.f) * 0.5f * Hf;
        float x0 = floorf(x), y0 = floorf(y);
        sx0[lvl][pt] = x0;  sy0[lvl][pt] = y0;
        swx1[lvl][pt] = x - x0;  swy1[lvl][pt] = y - y0;
        if (lvl == 0) sval[pt] = (z > 0.f) ? 1.f : 0.f;
    }
    __syncthreads();

    float cnt = 0.f;
    #pragma unroll
    for (int i = 0; i < 24; ++i) cnt += sval[i];
    cnt = fmaxf(cnt, 1.f);
    float icnt = 1.f / cnt;

    const int xi = t & 1;        // which x-tap this lane handles
    const int cb = t >> 1;       // channel slot 0..127 (covers cb and cb+128)
    const float xif = (float)xi;
    float acc0 = 0.f, acc1 = 0.f;

    #pragma unroll
    for (int lvl = 0; lvl < 2; ++lvl) {
        const int H = lvl ? 32 : 64;
        const int W = lvl ? 88 : 176;
        const int HW = H * W;
        const float* fm = lvl ? f1 : f0;

        float a0 = 0.f, a1 = 0.f;
        for (int i = 0; i < 24; ++i) {
            if (sval[i] == 0.f) continue;
            int v = i >> 2;
            float x0 = sx0[lvl][i], y0 = sy0[lvl][i];
            float wx1v = swx1[lvl][i], wy1v = swy1[lvl][i];
            float xw = xi ? wx1v : (1.f - wx1v);
            float wy0v = 1.f - wy1v;
            float xf = x0 + xif;
            if (!(xf >= 0.f && xf <= (float)(W - 1))) continue;
            int xc = (int)xf;
            const float* bse  = fm + ((size_t)(b * V + v) * C + cb) * (size_t)HW;
            const float* bse2 = bse + (size_t)128 * HW;
            if (y0 >= 0.f && y0 <= (float)(H - 1)) {
                int off = (int)y0 * W + xc;
                float pw = xw * wy0v;
                a0 += bse[off]  * pw;
                a1 += bse2[off] * pw;
            }
            float y1 = y0 + 1.f;
            if (y1 >= 0.f && y1 <= (float)(H - 1)) {
                int off = (int)y1 * W + xc;
                float pw = xw * wy1v;
                a0 += bse[off]  * pw;
                a1 += bse2[off] * pw;
            }
        }
        acc0 += a0 * icnt;
        acc1 += a1 * icnt;
    }
    acc0 *= 0.5f; acc1 *= 0.5f;
    acc0 += __shfl_xor(acc0, 1);
    acc1 += __shfl_xor(acc1, 1);
    float* outp = sampled + (size_t)(b * Q + q) * C;
    if (xi == 0) outp[cb] = acc0;
    else         outp[cb + 128] = acc1;
}

// Pack 4 weight matrices (W[n][k] fp32) into bf16 B-fragment order.
__global__ __launch_bounds__(256)
void wpack4(const float* __restrict__ W0, const float* __restrict__ W1,
            const float* __restrict__ W2, const float* __restrict__ W3,
            short* __restrict__ P0, short* __restrict__ P1,
            short* __restrict__ P2, short* __restrict__ P3)
{
    int gid = blockIdx.x * 256 + threadIdx.x;   // 32768 total
    int mat = gid >> 13;
    int rem = gid & 8191;
    int ks = rem >> 10;          // 0..7
    int nt = (rem >> 6) & 15;    // 0..15
    int lane = rem & 63;
    const float* W = (mat == 0) ? W0 : (mat == 1) ? W1 : (mat == 2) ? W2 : W3;
    short* P = (mat == 0) ? P0 : (mat == 1) ? P1 : (mat == 2) ? P2 : P3;
    int n = nt * 16 + (lane & 15);
    int k0 = ks * 32 + 8 * (lane >> 4);
    float4 a = *(const float4*)(W + (size_t)n * C + k0);
    float4 b = *(const float4*)(W + (size_t)n * C + k0 + 4);
    short8 s;
    s[0] = f2bf(a.x); s[1] = f2bf(a.y); s[2] = f2bf(a.z); s[3] = f2bf(a.w);
    s[4] = f2bf(b.x); s[5] = f2bf(b.y); s[6] = f2bf(b.z); s[7] = f2bf(b.w);
    *(short8*)(P + (size_t)((ks * 16 + nt) * 64 + lane) * 8) = s;
}

// MFMA GEMM: Y[m][n] = sum_k A[m][k]*W[n][k] + bias[n].
__device__ __forceinline__ void mgemm_body(const float* __restrict__ A,
                                           const short* __restrict__ Wp,
                                           const float* __restrict__ bias,
                                           float* __restrict__ Y,
                                           int m0, int n0t)
{
    __shared__ __align__(16) short As[64][264];
    const int tid = threadIdx.x;
    const int lane = tid & 63, w = tid >> 6;
    const int l15 = lane & 15, g = lane >> 4;

    {
        int r = tid & 63, part = tid >> 6;
        int gm = m0 + r;
        #pragma unroll
        for (int c = 0; c < 8; ++c) {
            int k = part * 64 + c * 8;
            float4 x = make_float4(0.f, 0.f, 0.f, 0.f);
            float4 y = make_float4(0.f, 0.f, 0.f, 0.f);
            if (gm < M_ROWS) {
                x = *(const float4*)(A + (size_t)gm * C + k);
                y = *(const float4*)(A + (size_t)gm * C + k + 4);
            }
            short8 s;
            s[0] = f2bf(x.x); s[1] = f2bf(x.y); s[2] = f2bf(x.z); s[3] = f2bf(x.w);
            s[4] = f2bf(y.x); s[5] = f2bf(y.y); s[6] = f2bf(y.z); s[7] = f2bf(y.w);
            *(short8*)&As[r][k] = s;
        }
    }
    __syncthreads();

    f32x4 acc[4];
    #pragma unroll
    for (int c = 0; c < 4; ++c) acc[c] = (f32x4){0.f, 0.f, 0.f, 0.f};

    #pragma unroll
    for (int ks = 0; ks < 8; ++ks) {
        short8 af = *(const short8*)&As[16 * w + l15][ks * 32 + 8 * g];
        #pragma unroll
        for (int c = 0; c < 4; ++c) {
            int nt = n0t * 4 + c;
            short8 bf = *(const short8*)(Wp + (size_t)((ks * 16 + nt) * 64 + lane) * 8);
            acc[c] = __builtin_amdgcn_mfma_f32_16x16x32_bf16(af, bf, acc[c], 0, 0, 0);
        }
    }

    #pragma unroll
    for (int c = 0; c < 4; ++c) {
        int n = n0t * 64 + c * 16 + l15;
        float bv = bias[n];
        #pragma unroll
        for (int j = 0; j < 4; ++j) {
            int gm = m0 + 16 * w + 4 * g + j;
            if (gm < M_ROWS) Y[(size_t)gm * C + n] = acc[c][j] + bv;
        }
    }
}

__global__ __launch_bounds__(256)
void gemm_qkv_mfma(const float* __restrict__ Xq, const float* __restrict__ Xs,
                   const short* __restrict__ Pq, const short* __restrict__ Pk,
                   const short* __restrict__ Pv,
                   const float* __restrict__ bq, const float* __restrict__ bk,
                   const float* __restrict__ bv,
                   float* __restrict__ Yq, float* __restrict__ Yk, float* __restrict__ Yv)
{
    int z = blockIdx.z;
    const float* A    = (z == 0) ? Xq : Xs;
    const short* Wp   = (z == 0) ? Pq : (z == 1) ? Pk : Pv;
    const float* bias = (z == 0) ? bq : (z == 1) ? bk : bv;
    float* Y          = (z == 0) ? Yq : (z == 1) ? Yk : Yv;
    mgemm_body(A, Wp, bias, Y, blockIdx.x * 64, blockIdx.y);
}

// O-projection with the split-K attention merge fused into A-staging:
// As[r][k] = bf16( (sum_s Opart[s][row][d]*e^{m_s-m}) / (sum_s l_s*e^{m_s-m}) )
// where k = h*32 + d.
__global__ __launch_bounds__(256)
void gemm_o_merge(const float* __restrict__ Opart, const float2* __restrict__ ml,
                  const short* __restrict__ Wp, const float* __restrict__ bias,
                  float* __restrict__ Y)
{
    __shared__ __align__(16) short As[64][264];
    const int tid = threadIdx.x;
    const int lane = tid & 63, w = tid >> 6;
    const int l15 = lane & 15, g = lane >> 4;
    const int m0 = blockIdx.x * 64, n0t = blockIdx.y;

    {
        int r = tid & 63, part = tid >> 6;
        int gm = m0 + r;
        if (gm < M_ROWS) {
            int bb = (gm >= Q) ? 1 : 0;
            int qq = gm - bb * Q;
            #pragma unroll
            for (int hh = 0; hh < 2; ++hh) {
                int h = 2 * part + hh;
                int rrow = (bb * NH + h) * Q + qq;
                float2 v[SPLITS];
                float m = -1e30f;
                #pragma unroll
                for (int s = 0; s < SPLITS; ++s) {
                    v[s] = ml[(size_t)s * RBH + rrow];
                    m = fmaxf(m, v[s].x);
                }
                float l = 0.f, wgt[SPLITS];
                #pragma unroll
                for (int s = 0; s < SPLITS; ++s) {
                    wgt[s] = __expf(v[s].x - m);
                    l += v[s].y * wgt[s];
                }
                float invl = 1.f / l;
                #pragma unroll
                for (int cc = 0; cc < 4; ++cc) {
                    int d0 = cc * 8;
                    float o[8] = {0.f,0.f,0.f,0.f,0.f,0.f,0.f,0.f};
                    #pragma unroll
                    for (int s = 0; s < SPLITS; ++s) {
                        const float* op = Opart + ((size_t)s * RBH + rrow) * 32 + d0;
                        float4 x = *(const float4*)op;
                        float4 y = *(const float4*)(op + 4);
                        o[0] += x.x * wgt[s]; o[1] += x.y * wgt[s];
                        o[2] += x.z * wgt[s]; o[3] += x.w * wgt[s];
                        o[4] += y.x * wgt[s]; o[5] += y.y * wgt[s];
                        o[6] += y.z * wgt[s]; o[7] += y.w * wgt[s];
                    }
                    short8 sv;
                    #pragma unroll
                    for (int j = 0; j < 8; ++j) sv[j] = f2bf(o[j] * invl);
                    *(short8*)&As[r][part * 64 + hh * 32 + d0] = sv;
                }
            }
        } else {
            #pragma unroll
            for (int c = 0; c < 8; ++c) {
                short8 z = {0,0,0,0,0,0,0,0};
                *(short8*)&As[r][part * 64 + c * 8] = z;
            }
        }
    }
    __syncthreads();

    f32x4 acc[4];
    #pragma unroll
    for (int c = 0; c < 4; ++c) acc[c] = (f32x4){0.f, 0.f, 0.f, 0.f};

    #pragma unroll
    for (int ks = 0; ks < 8; ++ks) {
        short8 af = *(const short8*)&As[16 * w + l15][ks * 32 + 8 * g];
        #pragma unroll
        for (int c = 0; c < 4; ++c) {
            int nt = n0t * 4 + c;
            short8 bf = *(const short8*)(Wp + (size_t)((ks * 16 + nt) * 64 + lane) * 8);
            acc[c] = __builtin_amdgcn_mfma_f32_16x16x32_bf16(af, bf, acc[c], 0, 0, 0);
        }
    }

    #pragma unroll
    for (int c = 0; c < 4; ++c) {
        int n = n0t * 64 + c * 16 + l15;
        float bv = bias[n];
        #pragma unroll
        for (int j = 0; j < 4; ++j) {
            int gm = m0 + 16 * w + 4 * g + j;
            if (gm < M_ROWS) Y[(size_t)gm * C + n] = acc[c][j] + bv;
        }
    }
}

// Split-K MFMA flash attention (unchanged from round 7).
__global__ __launch_bounds__(128)
void attn_mfma_split(const float* __restrict__ qb, const float* __restrict__ kb,
                     const float* __restrict__ vb,
                     float* __restrict__ Opart, float2* __restrict__ ml)
{
    __shared__ __align__(16) short Ks[2][32][40];   // [buf][key][dim]
    __shared__ __align__(16) short VT[2][32][36];   // [buf][dim][key]

    const int tid = threadIdx.x;
    const int lane = tid & 63;
    const int w = tid >> 6;
    const int l15 = lane & 15, g = lane >> 4;
    const int bz = blockIdx.z;
    const int b = bz >> 2, s = bz & 3;
    const int h = blockIdx.y;
    const int q0 = blockIdx.x * 32 + w * 16;
    const int t0 = s * TPS;
    const int t1 = (t0 + TPS < NT) ? (t0 + TPS) : NT;

    short8 qf;
    {
        const float sc = 0.17677669529663687f; // 1/sqrt(32)
        int qrow = q0 + l15;
        float4 a = make_float4(0.f,0.f,0.f,0.f), c2 = make_float4(0.f,0.f,0.f,0.f);
        if (qrow < Q) {
            const float* p = qb + (size_t)(b * Q + qrow) * C + h * HD + 8 * g;
            a  = *(const float4*)p;
            c2 = *(const float4*)(p + 4);
        }
        qf[0]=f2bf(a.x*sc);  qf[1]=f2bf(a.y*sc);  qf[2]=f2bf(a.z*sc);  qf[3]=f2bf(a.w*sc);
        qf[4]=f2bf(c2.x*sc); qf[5]=f2bf(c2.y*sc); qf[6]=f2bf(c2.z*sc); qf[7]=f2bf(c2.w*sc);
    }

    float m_ = -1e30f, l_ = 0.f;
    f32x4 acc0 = {0.f,0.f,0.f,0.f}, acc1 = {0.f,0.f,0.f,0.f};
    const f32x4 z4 = {0.f,0.f,0.f,0.f};

    const int keyA = tid >> 3,        ccA = tid & 7;
    const int keyB = (128 + tid) >> 3, ccB = tid & 7;
    float4 kregA, vregA, kregB, vregB;

    #define LOAD_TILE(t)                                                        \
    {                                                                           \
        int gkA = (t) * 32 + keyA, gkB = (t) * 32 + keyB;                       \
        if (gkA < Q) {                                                          \
            const float* kp = kb + (size_t)(b*Q+gkA)*C + h*HD + 4*ccA;          \
            const float* vp = vb + (size_t)(b*Q+gkA)*C + h*HD + 4*ccA;          \
            kregA = *(const float4*)kp; vregA = *(const float4*)vp;             \
        } else { kregA = make_float4(0.f,0.f,0.f,0.f); vregA = kregA; }         \
        if (gkB < Q) {                                                          \
            const float* kp = kb + (size_t)(b*Q+gkB)*C + h*HD + 4*ccB;          \
            const float* vp = vb + (size_t)(b*Q+gkB)*C + h*HD + 4*ccB;          \
            kregB = *(const float4*)kp; vregB = *(const float4*)vp;             \
        } else { kregB = make_float4(0.f,0.f,0.f,0.f); vregB = kregB; }         \
    }

    #define WRITE_LDS(bi)                                                       \
    {                                                                           \
        short4 ks;                                                              \
        ks.x = f2bf(kregA.x); ks.y = f2bf(kregA.y); ks.z = f2bf(kregA.z); ks.w = f2bf(kregA.w); \
        *(short4*)&Ks[bi][keyA][4 * ccA] = ks;                                  \
        VT[bi][4*ccA+0][keyA] = f2bf(vregA.x);                                  \
        VT[bi][4*ccA+1][keyA] = f2bf(vregA.y);                                  \
        VT[bi][4*ccA+2][keyA] = f2bf(vregA.z);                                  \
        VT[bi][4*ccA+3][keyA] = f2bf(vregA.w);                                  \
        ks.x = f2bf(kregB.x); ks.y = f2bf(kregB.y); ks.z = f2bf(kregB.z); ks.w = f2bf(kregB.w); \
        *(short4*)&Ks[bi][keyB][4 * ccB] = ks;                                  \
        VT[bi][4*ccB+0][keyB] = f2bf(vregB.x);                                  \
        VT[bi][4*ccB+1][keyB] = f2bf(vregB.y);                                  \
        VT[bi][4*ccB+2][keyB] = f2bf(vregB.z);                                  \
        VT[bi][4*ccB+3][keyB] = f2bf(vregB.w);                                  \
    }

    LOAD_TILE(t0);
    WRITE_LDS(0);
    __syncthreads();

    for (int t = t0; t < t1; ++t) {
        const int buf = (t - t0) & 1;
        if (t + 1 < t1) LOAD_TILE(t + 1);

        short8 kf0 = *(const short8*)&Ks[buf][l15][8 * g];
        short8 kf1 = *(const short8*)&Ks[buf][16 + l15][8 * g];
        f32x4 s0 = __builtin_amdgcn_mfma_f32_16x16x32_bf16(kf0, qf, z4, 0, 0, 0);
        f32x4 s1 = __builtin_amdgcn_mfma_f32_16x16x32_bf16(kf1, qf, z4, 0, 0, 0);

        const int kbase = t * 32;
        if (kbase + 32 > Q) {
            #pragma unroll
            for (int j = 0; j < 4; ++j) {
                if (kbase + 4 * g + j      >= Q) s0[j] = -1e30f;
                if (kbase + 16 + 4 * g + j >= Q) s1[j] = -1e30f;
            }
        }

        float tm = fmaxf(fmaxf(fmaxf(s0[0], s0[1]), fmaxf(s0[2], s0[3])),
                         fmaxf(fmaxf(s1[0], s1[1]), fmaxf(s1[2], s1[3])));
        tm = fmaxf(tm, __shfl_xor(tm, 16));
        tm = fmaxf(tm, __shfl_xor(tm, 32));
        float mn = fmaxf(m_, tm);
        float al = __expf(m_ - mn);
        m_ = mn;
        float p0 = __expf(s0[0]-mn), p1 = __expf(s0[1]-mn), p2 = __expf(s0[2]-mn), p3 = __expf(s0[3]-mn);
        float p4 = __expf(s1[0]-mn), p5 = __expf(s1[1]-mn), p6 = __expf(s1[2]-mn), p7 = __expf(s1[3]-mn);
        float ps = ((p0+p1)+(p2+p3)) + ((p4+p5)+(p6+p7));
        ps += __shfl_xor(ps, 16);
        ps += __shfl_xor(ps, 32);
        l_ = l_ * al + ps;

        #pragma unroll
        for (int j = 0; j < 4; ++j) {
            float alr = __shfl(al, 4 * g + j);
            acc0[j] *= alr;
            acc1[j] *= alr;
        }

        short8 pf;
        pf[0]=f2bf(p0); pf[1]=f2bf(p1); pf[2]=f2bf(p2); pf[3]=f2bf(p3);
        pf[4]=f2bf(p4); pf[5]=f2bf(p5); pf[6]=f2bf(p6); pf[7]=f2bf(p7);

        short4 va  = *(const short4*)&VT[buf][l15][4 * g];
        short4 vb2 = *(const short4*)&VT[buf][l15][16 + 4 * g];
        short4 vc  = *(const short4*)&VT[buf][16 + l15][4 * g];
        short4 vd  = *(const short4*)&VT[buf][16 + l15][16 + 4 * g];
        short8 vf0, vf1;
        vf0[0]=va.x;  vf0[1]=va.y;  vf0[2]=va.z;  vf0[3]=va.w;
        vf0[4]=vb2.x; vf0[5]=vb2.y; vf0[6]=vb2.z; vf0[7]=vb2.w;
        vf1[0]=vc.x;  vf1[1]=vc.y;  vf1[2]=vc.z;  vf1[3]=vc.w;
        vf1[4]=vd.x;  vf1[5]=vd.y;  vf1[6]=vd.z;  vf1[7]=vd.w;
        acc0 = __builtin_amdgcn_mfma_f32_16x16x32_bf16(pf, vf0, acc0, 0, 0, 0);
        acc1 = __builtin_amdgcn_mfma_f32_16x16x32_bf16(pf, vf1, acc1, 0, 0, 0);

        if (t + 1 < t1) WRITE_LDS(buf ^ 1);
        __syncthreads();
    }

    const size_t rowbase = (size_t)((s * B + b) * NH + h) * Q;
    float* op = Opart + rowbase * 32;
    #pragma unroll
    for (int j = 0; j < 4; ++j) {
        int qrow = q0 + 4 * g + j;
        if (qrow < Q) {
            op[(size_t)qrow * 32 + l15]      = acc0[j];
            op[(size_t)qrow * 32 + 16 + l15] = acc1[j];
        }
    }
    if (g == 0 && q0 + l15 < Q) ml[rowbase + q0 + l15] = make_float2(m_, l_);
    #undef LOAD_TILE
    #undef WRITE_LDS
}

extern "C" void kernel_launch(void* const* d_in, const int* in_sizes, int n_in,
                              void* d_out, int out_size, void* d_ws, size_t ws_size,
                              hipStream_t stream) {
    const float* f0   = (const float*)d_in[0];
    const float* f1   = (const float*)d_in[1];
    const float* refs = (const float*)d_in[2];
    const float* intr = (const float*)d_in[3];
    const float* extr = (const float*)d_in[4];
    const float* qin  = (const float*)d_in[5];
    const float* Wq   = (const float*)d_in[6];
    const float* bq   = (const float*)d_in[7];
    const float* Wk   = (const float*)d_in[8];
    const float* bk   = (const float*)d_in[9];
    const float* Wv   = (const float*)d_in[10];
    const float* bv   = (const float*)d_in[11];
    const float* Wo   = (const float*)d_in[12];
    const float* bo   = (const float*)d_in[13];

    float* ws      = (float*)d_ws;
    float* sampled = ws;                  // 460800 each
    float* qbuf    = sampled + 460800;
    float* kbuf    = qbuf    + 460800;
    float* vbuf    = kbuf    + 460800;
    float* obuf    = vbuf    + 460800;    // (unused, kept for layout)
    short* Pq      = (short*)(obuf + 460800);   // 65536 bf16 each
    short* Pk      = Pq + 65536;
    short* Pv      = Pk + 65536;
    short* Po      = Pv + 65536;
    float* Opart   = obuf + 460800 + 131072;    // SPLITS*RBH*32 f32
    float2* ml     = (float2*)(Opart + (size_t)SPLITS * RBH * 32);
    float* out     = (float*)d_out;

    wpack4<<<128, 256, 0, stream>>>(Wq, Wk, Wv, Wo, Pq, Pk, Pv, Po);

    sampler_kernel<<<B * Q, 256, 0, stream>>>(f0, f1, refs, intr, extr, sampled);

    dim3 ggrid((M_ROWS + 63) / 64, C / 64, 3);
    gemm_qkv_mfma<<<ggrid, 256, 0, stream>>>(qin, sampled, Pq, Pk, Pv,
                                             bq, bk, bv, qbuf, kbuf, vbuf);

    dim3 agrid((Q + 31) / 32, NH, B * SPLITS);
    attn_mfma_split<<<agrid, 128, 0, stream>>>(qbuf, kbuf, vbuf, Opart, ml);

    dim3 ogrid((M_ROWS + 63) / 64, C / 64, 1);
    gemm_o_merge<<<ogrid, 256, 0, stream>>>(Opart, ml, Po, bo, out);
}